// Round 11
// baseline (302.515 us; speedup 1.0000x reference)
//
#include <hip/hip_runtime.h>
#include <math.h>

#define C 128
#define ASTRIDE 132   // padded LDS acc row stride (f32) to spread banks

typedef __attribute__((ext_vector_type(8))) short short8;
typedef __attribute__((ext_vector_type(4))) float f32x4;
typedef __attribute__((ext_vector_type(4))) unsigned short ushort4_t;
typedef __attribute__((ext_vector_type(8))) unsigned short ushort8_t;

__device__ inline unsigned short f2b(float f) {
    union { float f; unsigned int u; } v; v.f = f;
    unsigned int u = v.u;
    return (unsigned short)((u + 0x7FFFu + ((u >> 16) & 1u)) >> 16);  // RNE
}
__device__ inline float bits2f(unsigned int u) {
    union { unsigned int u; float f; } v; v.u = u; return v.f;
}

// accumulate 8 bf16 (packed in uint4) scaled by s into a[0..7]
__device__ inline void acc8(float* a, uint4 u, float s) {
    a[0] += s * bits2f(u.x << 16); a[1] += s * bits2f(u.x & 0xFFFF0000u);
    a[2] += s * bits2f(u.y << 16); a[3] += s * bits2f(u.y & 0xFFFF0000u);
    a[4] += s * bits2f(u.z << 16); a[5] += s * bits2f(u.z & 0xFFFF0000u);
    a[6] += s * bits2f(u.w << 16); a[7] += s * bits2f(u.w & 0xFFFF0000u);
}

// ================= CSR build: count -> scan -> place =================

__global__ void k_zero(int* __restrict__ cnt, int n) {
    int i = blockIdx.x * blockDim.x + threadIdx.x;
    if (i < n) cnt[i] = 0;
}

__global__ void k_cnt(const int* __restrict__ dst, int* __restrict__ cnt, int e) {
    int i = blockIdx.x * blockDim.x + threadIdx.x;
    if (i < e) atomicAdd(&cnt[dst[i]], 1);
}

// per-256-block exclusive scan; rowbeg gets local exclusive, blocksum gets block total
__global__ __launch_bounds__(256) void k_scan_a(const int* __restrict__ cnt,
                                                int* __restrict__ rowbeg,
                                                int* __restrict__ blocksum, int n) {
    const int tid = threadIdx.x;
    const int i = blockIdx.x * 256 + tid;
    const int lane = tid & 63, wv = tid >> 6;
    int v = (i < n) ? cnt[i] : 0;
    int x = v;
    #pragma unroll
    for (int off = 1; off < 64; off <<= 1) {
        int y = __shfl_up(x, off, 64);
        if (lane >= off) x += y;
    }
    __shared__ int wsum[4];
    if (lane == 63) wsum[wv] = x;
    __syncthreads();
    int woff = 0;
    #pragma unroll
    for (int k = 0; k < 4; ++k) if (k < wv) woff += wsum[k];
    int incl = x + woff;
    if (i < n) rowbeg[i] = incl - v;
    if (tid == 255) blocksum[blockIdx.x] = incl;
}

// single-block scan of blocksums (nb <= 512) -> exclusive offsets in place
__global__ __launch_bounds__(512) void k_scan_b(int* __restrict__ bs, int nb) {
    const int tid = threadIdx.x;
    __shared__ int s[512];
    int v = (tid < nb) ? bs[tid] : 0;
    s[tid] = v;
    __syncthreads();
    for (int off = 1; off < 512; off <<= 1) {
        int t = 0;
        if (tid >= off) t = s[tid - off];
        __syncthreads();
        s[tid] += t;
        __syncthreads();
    }
    if (tid < nb) bs[tid] = s[tid] - v;  // exclusive
}

// add block offsets; init rowcur; compute dis; write rowbeg[n]
__global__ void k_scan_c(const int* __restrict__ cnt, const int* __restrict__ bs,
                         int* __restrict__ rowbeg, int* __restrict__ rowcur,
                         float* __restrict__ dis, int n) {
    int i = blockIdx.x * blockDim.x + threadIdx.x;
    if (i >= n) return;
    int rb = rowbeg[i] + bs[i >> 8];
    rowbeg[i] = rb;
    rowcur[i] = rb;
    dis[i] = rsqrtf((float)cnt[i] + 1.0f);
    if (i == n - 1) rowbeg[n] = rb + cnt[i];
}

__global__ void k_place(const int* __restrict__ src, const int* __restrict__ dst,
                        const float* __restrict__ ew, const float* __restrict__ dis,
                        int* __restrict__ rowcur, int2* __restrict__ edata, int e) {
    int i = blockIdx.x * blockDim.x + threadIdx.x;
    if (i >= e) return;
    int s = src[i], d = dst[i];
    int p = atomicAdd(&rowcur[d], 1);
    float w = dis[s] * ew[i] * dis[d];
    union { float f; int i; } wb; wb.f = w;
    edata[p] = make_int2(s, wb.i);
}

// ================= W pack =================
__global__ void k_pack_w2(const float* __restrict__ W1, const float* __restrict__ W2,
                          unsigned short* __restrict__ W1p, unsigned short* __restrict__ W2p) {
    int idx = blockIdx.x * blockDim.x + threadIdx.x;
    const float* W = (idx < C * C) ? W1 : W2;
    unsigned short* Wp = (idx < C * C) ? W1p : W2p;
    int p = idx & (C * C - 1);
    int j = p & 7;
    int l = (p >> 3) & 63;
    int t = p >> 9;           // ct*4 + ks
    int ks = t & 3, ct = t >> 2;
    int k = ks * 32 + ((l >> 4) << 3) + j;
    int c = (ct << 4) + (l & 15);
    Wp[p] = f2b(W[k * C + c]);
}

// ================= MFMA GEMM: Hb = bf16(X @ W) =================
__global__ __launch_bounds__(256) void k_gemm_mfma(
    const float* __restrict__ X, const unsigned short* __restrict__ Wp,
    unsigned short* __restrict__ Hb, int n) {
    __shared__ unsigned short xs[32 * C];
    const int tid = threadIdx.x;
    const int base = blockIdx.x * 32;

    const float4* Xv = (const float4*)(X + (size_t)base * C);
    #pragma unroll
    for (int i = 0; i < 4; ++i) {
        int idx4 = i * 256 + tid;
        int elem = idx4 * 4;
        int r = elem >> 7, c = elem & 127;
        float4 v = make_float4(0.f, 0.f, 0.f, 0.f);
        if (base + r < n) v = Xv[idx4];
        ushort4_t pkt;
        pkt.x = f2b(v.x); pkt.y = f2b(v.y); pkt.z = f2b(v.z); pkt.w = f2b(v.w);
        int byte = (r * 256 + c * 2) ^ ((r & 7) << 4);
        *(ushort4_t*)((char*)xs + byte) = pkt;
    }
    __syncthreads();

    const int lane = tid & 63;
    const int wid = tid >> 6;
    const int wm = wid >> 1;
    const int wn = wid & 1;
    const int arow = wm * 16 + (lane & 15);
    const int kg = lane >> 4;

    f32x4 acc[4] = {f32x4{0,0,0,0}, f32x4{0,0,0,0}, f32x4{0,0,0,0}, f32x4{0,0,0,0}};

    #pragma unroll
    for (int ks = 0; ks < 4; ++ks) {
        int abyte = (arow * 256 + ks * 64 + kg * 16) ^ ((arow & 7) << 4);
        short8 a = *(const short8*)((const char*)xs + abyte);
        #pragma unroll
        for (int nt = 0; nt < 4; ++nt) {
            int ct = wn * 4 + nt;
            short8 b = *(const short8*)(Wp + (size_t)((ct * 4 + ks) * 64 + lane) * 8);
            acc[nt] = __builtin_amdgcn_mfma_f32_16x16x32_bf16(a, b, acc[nt], 0, 0, 0);
        }
    }

    const int rbase = base + wm * 16 + kg * 4;
    #pragma unroll
    for (int nt = 0; nt < 4; ++nt) {
        int col = wn * 64 + nt * 16 + (lane & 15);
        #pragma unroll
        for (int r = 0; r < 4; ++r) {
            int row = rbase + r;
            if (row >= n) continue;
            Hb[(size_t)row * C + col] = f2b(acc[nt][r]);
        }
    }
}

// ================= balanced block aggregation helpers =================
// acc LDS [32][ASTRIDE] f32; bnd[33] = CSR boundaries of the block's 32 rows.

// init: acc[row] = dis^2 * Hb[row] + bias  (8 threads/row, 16 cols each)
__device__ inline void block_agg_init(float* __restrict__ acc,
    const unsigned short* __restrict__ Hb, const float* __restrict__ dis,
    const float* __restrict__ bias, int base, int n, int tid) {
    int row = tid >> 3, part = tid & 7, ci = part * 16;
    int grow = base + row;
    float aa[16];
    #pragma unroll
    for (int j = 0; j < 16; ++j) aa[j] = 0.f;
    if (grow < n) {
        float d = dis[grow];
        float d2 = d * d;
        const unsigned short* hr = Hb + (size_t)grow * C + ci;
        uint4 h0 = *(const uint4*)hr;
        uint4 h1 = *(const uint4*)(hr + 8);
        acc8(aa, h0, d2);
        acc8(aa + 8, h1, d2);
        #pragma unroll
        for (int q = 0; q < 4; ++q) {
            float4 bv = *(const float4*)(bias + ci + q * 4);
            aa[q*4+0] += bv.x; aa[q*4+1] += bv.y; aa[q*4+2] += bv.z; aa[q*4+3] += bv.w;
        }
    }
    float* ap = acc + row * ASTRIDE + ci;
    #pragma unroll
    for (int q = 0; q < 4; ++q)
        *(float4*)(ap + q * 4) = make_float4(aa[q*4], aa[q*4+1], aa[q*4+2], aa[q*4+3]);
}

// edge phase: 16 lane-groups each take len/16 contiguous edges; flush on dst change
__device__ inline void block_agg_edges(float* __restrict__ acc, const int* __restrict__ bnd,
    const int2* __restrict__ edata, const unsigned short* __restrict__ Hb, int tid) {
    const int grpId = tid >> 4;
    const int sub = tid & 15;
    const int c0 = sub * 8;
    const int estart = bnd[0];
    const int len = bnd[32] - estart;
    int eg  = estart + (int)(((long long)len * grpId) >> 4);
    int egE = estart + (int)(((long long)len * (grpId + 1)) >> 4);

    int dstloc = 0;
    while (dstloc < 31 && eg >= bnd[dstloc + 1]) ++dstloc;
    int nextB = bnd[dstloc + 1];

    float a[8];
    #pragma unroll
    for (int j = 0; j < 8; ++j) a[j] = 0.f;

    auto proc = [&](int idx, int2 eD, uint4 u) {
        while (idx >= nextB) {
            #pragma unroll
            for (int j = 0; j < 8; ++j) {
                atomicAdd(&acc[dstloc * ASTRIDE + c0 + j], a[j]);
                a[j] = 0.f;
            }
            ++dstloc;
            nextB = bnd[dstloc + 1];
        }
        acc8(a, u, bits2f((unsigned int)eD.y));
    };

    int ei = eg;
    while (ei + 4 <= egE) {
        int2 e0 = edata[ei], e1 = edata[ei + 1], e2 = edata[ei + 2], e3 = edata[ei + 3];
        uint4 u0 = *(const uint4*)(Hb + (size_t)e0.x * C + c0);
        uint4 u1 = *(const uint4*)(Hb + (size_t)e1.x * C + c0);
        uint4 u2 = *(const uint4*)(Hb + (size_t)e2.x * C + c0);
        uint4 u3 = *(const uint4*)(Hb + (size_t)e3.x * C + c0);
        proc(ei, e0, u0);
        proc(ei + 1, e1, u1);
        proc(ei + 2, e2, u2);
        proc(ei + 3, e3, u3);
        ei += 4;
    }
    while (ei < egE) {
        int2 e0 = edata[ei];
        uint4 u0 = *(const uint4*)(Hb + (size_t)e0.x * C + c0);
        proc(ei, e0, u0);
        ++ei;
    }
    #pragma unroll
    for (int j = 0; j < 8; ++j) atomicAdd(&acc[dstloc * ASTRIDE + c0 + j], a[j]);
}

// LN + GELU from LDS acc: 8 threads/row, 16 cols each -> t[16]
__device__ inline void block_ln_gelu(const float* __restrict__ acc,
    const float* __restrict__ g, const float* __restrict__ beta,
    int row, int ci, float* t) {
    const float* ap = acc + row * ASTRIDE + ci;
    float aa[16];
    #pragma unroll
    for (int q = 0; q < 4; ++q) {
        float4 v = *(const float4*)(ap + q * 4);
        aa[q*4] = v.x; aa[q*4+1] = v.y; aa[q*4+2] = v.z; aa[q*4+3] = v.w;
    }
    float s = 0.f, sq = 0.f;
    #pragma unroll
    for (int j = 0; j < 16; ++j) { s += aa[j]; sq += aa[j] * aa[j]; }
    #pragma unroll
    for (int off = 4; off >= 1; off >>= 1) {
        s  += __shfl_xor(s, off, 64);
        sq += __shfl_xor(sq, off, 64);
    }
    float mu = s * (1.0f / C);
    float var = sq * (1.0f / C) - mu * mu;
    float rstd = rsqrtf(var + 1e-5f);
    #pragma unroll
    for (int q = 0; q < 4; ++q) {
        float4 gv = *(const float4*)(g + ci + q * 4);
        float4 bv = *(const float4*)(beta + ci + q * 4);
        float gg[4] = {gv.x, gv.y, gv.z, gv.w};
        float bb[4] = {bv.x, bv.y, bv.z, bv.w};
        #pragma unroll
        for (int j = 0; j < 4; ++j) {
            float v = (aa[q*4+j] - mu) * rstd * gg[j] + bb[j];
            t[q*4+j] = 0.5f * v * (1.0f + erff(v * 0.70710678118654752f));
        }
    }
}

// ================= fused: balanced agg + LN + GELU -> LDS -> GEMM (W2) =================
__global__ __launch_bounds__(256) void k_fused_agg_gemm(
    const int* __restrict__ rowbeg, const int2* __restrict__ edata,
    const unsigned short* __restrict__ Hb_in, const float* __restrict__ dis,
    const float* __restrict__ bias, const float* __restrict__ g,
    const float* __restrict__ beta,
    const unsigned short* __restrict__ Wp, unsigned short* __restrict__ Hb_out, int n) {
    __shared__ float acc[32 * ASTRIDE];
    __shared__ int bnd[33];
    __shared__ unsigned short xs[32 * C];
    const int tid = threadIdx.x;
    const int base = blockIdx.x * 32;

    if (tid < 33) {
        int r = base + tid;
        bnd[tid] = rowbeg[r > n ? n : r];
    }
    block_agg_init(acc, Hb_in, dis, bias, base, n, tid);
    __syncthreads();
    block_agg_edges(acc, bnd, edata, Hb_in, tid);
    __syncthreads();

    // LN + GELU -> bf16 swizzled LDS
    {
        int row = tid >> 3, sub = tid & 7, ci = sub * 16;
        float t[16];
        block_ln_gelu(acc, g, beta, row, ci, t);
        ushort8_t p0, p1;
        #pragma unroll
        for (int j = 0; j < 8; ++j) { p0[j] = f2b(t[j]); p1[j] = f2b(t[j + 8]); }
        int lin = row * 256 + ci * 2;
        *(ushort8_t*)((char*)xs + (lin ^ ((row & 7) << 4))) = p0;
        *(ushort8_t*)((char*)xs + ((lin + 16) ^ ((row & 7) << 4))) = p1;
    }
    __syncthreads();

    // GEMM phase
    const int lane = tid & 63;
    const int wid = tid >> 6;
    const int wm = wid >> 1;
    const int wn = wid & 1;
    const int arow = wm * 16 + (lane & 15);
    const int kg = lane >> 4;

    f32x4 ac[4] = {f32x4{0,0,0,0}, f32x4{0,0,0,0}, f32x4{0,0,0,0}, f32x4{0,0,0,0}};

    #pragma unroll
    for (int ks = 0; ks < 4; ++ks) {
        int abyte = (arow * 256 + ks * 64 + kg * 16) ^ ((arow & 7) << 4);
        short8 av = *(const short8*)((const char*)xs + abyte);
        #pragma unroll
        for (int nt = 0; nt < 4; ++nt) {
            int ct = wn * 4 + nt;
            short8 bv = *(const short8*)(Wp + (size_t)((ct * 4 + ks) * 64 + lane) * 8);
            ac[nt] = __builtin_amdgcn_mfma_f32_16x16x32_bf16(av, bv, ac[nt], 0, 0, 0);
        }
    }

    const int rbase = base + wm * 16 + kg * 4;
    #pragma unroll
    for (int nt = 0; nt < 4; ++nt) {
        int col = wn * 64 + nt * 16 + (lane & 15);
        #pragma unroll
        for (int r = 0; r < 4; ++r) {
            int row = rbase + r;
            if (row >= n) continue;
            Hb_out[(size_t)row * C + col] = f2b(ac[nt][r]);
        }
    }
}

// ================= final: balanced agg + LN + GELU + residual -> f32 out =================
__global__ __launch_bounds__(256) void k_agg_ln_gelu(
    const int* __restrict__ rowbeg, const int2* __restrict__ edata,
    const unsigned short* __restrict__ Hb, const float* __restrict__ dis,
    const float* __restrict__ bias, const float* __restrict__ g,
    const float* __restrict__ beta, const float* __restrict__ resid,
    float* __restrict__ Out, int n) {
    __shared__ float acc[32 * ASTRIDE];
    __shared__ int bnd[33];
    const int tid = threadIdx.x;
    const int base = blockIdx.x * 32;

    if (tid < 33) {
        int r = base + tid;
        bnd[tid] = rowbeg[r > n ? n : r];
    }
    block_agg_init(acc, Hb, dis, bias, base, n, tid);
    __syncthreads();
    block_agg_edges(acc, bnd, edata, Hb, tid);
    __syncthreads();

    int row = tid >> 3, sub = tid & 7, ci = sub * 16;
    int grow = base + row;
    float t[16];
    block_ln_gelu(acc, g, beta, row, ci, t);
    if (grow < n) {
        const float* rp = resid + (size_t)grow * C + ci;
        float* op = Out + (size_t)grow * C + ci;
        #pragma unroll
        for (int q = 0; q < 4; ++q) {
            float4 rv = *(const float4*)(rp + q * 4);
            *(float4*)(op + q * 4) = make_float4(t[q*4] + rv.x, t[q*4+1] + rv.y,
                                                 t[q*4+2] + rv.z, t[q*4+3] + rv.w);
        }
    }
}

// ================= launch =================

extern "C" void kernel_launch(void* const* d_in, const int* in_sizes, int n_in,
                              void* d_out, int out_size, void* d_ws, size_t ws_size,
                              hipStream_t stream) {
    const float* x      = (const float*)d_in[0];
    const int*   eidx   = (const int*)d_in[1];
    const float* ew     = (const float*)d_in[2];
    const float* W1     = (const float*)d_in[3];
    const float* b1     = (const float*)d_in[4];
    const float* g1     = (const float*)d_in[5];
    const float* beta1  = (const float*)d_in[6];
    const float* W2     = (const float*)d_in[7];
    const float* b2     = (const float*)d_in[8];
    const float* g2     = (const float*)d_in[9];
    const float* beta2  = (const float*)d_in[10];

    const int n = in_sizes[0] / C;
    const int e = in_sizes[2];
    const int* src = eidx;
    const int* dst = eidx + e;

    float* out = (float*)d_out;

    // workspace layout (256B-aligned chunks)
    char* p = (char*)d_ws;
    auto alloc = [&](size_t bytes) {
        char* q = p;
        p += (bytes + 255) & ~(size_t)255;
        return q;
    };
    float* dis      = (float*)alloc(sizeof(float) * n);
    int*   cnt      = (int*)alloc(sizeof(int) * n);
    int*   rowbeg   = (int*)alloc(sizeof(int) * (n + 1));
    int*   rowcur   = (int*)alloc(sizeof(int) * n);
    int*   blocksum = (int*)alloc(sizeof(int) * 512);
    int2*  edata    = (int2*)alloc(sizeof(int2) * e);
    unsigned short* Hb1 = (unsigned short*)alloc(sizeof(unsigned short) * (size_t)n * C);
    unsigned short* Hb2 = (unsigned short*)alloc(sizeof(unsigned short) * (size_t)n * C);
    unsigned short* W1p = (unsigned short*)alloc(sizeof(unsigned short) * C * C);
    unsigned short* W2p = (unsigned short*)alloc(sizeof(unsigned short) * C * C);

    const int B = 256;
    const int gn = (n + B - 1) / B;   // also the scan block count (must be <= 512)
    const int ge = (e + B - 1) / B;

    // CSR build (row-ordered segments via prefix sum)
    k_zero<<<gn, B, 0, stream>>>(cnt, n);
    k_cnt<<<ge, B, 0, stream>>>(dst, cnt, e);
    k_scan_a<<<gn, B, 0, stream>>>(cnt, rowbeg, blocksum, n);
    k_scan_b<<<1, 512, 0, stream>>>(blocksum, gn);
    k_scan_c<<<gn, B, 0, stream>>>(cnt, blocksum, rowbeg, rowcur, dis, n);
    k_place<<<ge, B, 0, stream>>>(src, dst, ew, dis, rowcur, edata, e);

    // pack weights
    k_pack_w2<<<(2 * C * C) / B, B, 0, stream>>>(W1, W2, W1p, W2p);

    // layer-1 GEMM: Hb1 = bf16(x @ W1)
    k_gemm_mfma<<<(n + 31) / 32, B, 0, stream>>>(x, W1p, Hb1, n);

    // fused: h_act1 = GELU(LN(agg(Hb1)+b1)); Hb2 = bf16(h_act1 @ W2)
    k_fused_agg_gemm<<<(n + 31) / 32, B, 0, stream>>>(rowbeg, edata, Hb1, dis,
                                                      b1, g1, beta1, W2p, Hb2, n);

    // final: out = GELU(LN(agg(Hb2)+b2)) + x
    k_agg_ln_gelu<<<(n + 31) / 32, B, 0, stream>>>(rowbeg, edata, Hb2, dis,
                                                   b2, g2, beta2, x, out, n);
}

// Round 12
// 186.786 us; speedup vs baseline: 1.6196x; 1.6196x over previous
//
#include <hip/hip_runtime.h>
#include <math.h>

#define C 128

typedef __attribute__((ext_vector_type(8))) short short8;
typedef __attribute__((ext_vector_type(4))) float f32x4;
typedef __attribute__((ext_vector_type(4))) unsigned short ushort4_t;
typedef __attribute__((ext_vector_type(8))) unsigned short ushort8_t;

__device__ inline unsigned short f2b(float f) {
    union { float f; unsigned int u; } v; v.f = f;
    unsigned int u = v.u;
    return (unsigned short)((u + 0x7FFFu + ((u >> 16) & 1u)) >> 16);  // RNE
}
__device__ inline float bits2f(unsigned int u) {
    union { unsigned int u; float f; } v; v.u = u; return v.f;
}

// accumulate 8 bf16 (packed in uint4) scaled by s into a[0..7]
__device__ inline void acc8(float* a, uint4 u, float s) {
    a[0] += s * bits2f(u.x << 16); a[1] += s * bits2f(u.x & 0xFFFF0000u);
    a[2] += s * bits2f(u.y << 16); a[3] += s * bits2f(u.y & 0xFFFF0000u);
    a[4] += s * bits2f(u.z << 16); a[5] += s * bits2f(u.z & 0xFFFF0000u);
    a[6] += s * bits2f(u.w << 16); a[7] += s * bits2f(u.w & 0xFFFF0000u);
}

// ---------------- shared row worker: aggregate + bias + LN + GELU ----------------
// 16 lanes cooperate on one row; this lane covers cols c0..c0+7. Result in t[8].
__device__ inline void agg_ln_gelu_row(
    int row, int c0,
    const int* __restrict__ rowbeg, const int* __restrict__ rowend,
    const int2* __restrict__ edata, const unsigned short* __restrict__ Hb,
    const float* __restrict__ dis, const float* __restrict__ bias,
    const float* __restrict__ g, const float* __restrict__ beta, float* t) {
    float a[8] = {0.f, 0.f, 0.f, 0.f, 0.f, 0.f, 0.f, 0.f};

    // self-loop: dis^2 * Hb[row]
    {
        float d = dis[row];
        uint4 hu = *(const uint4*)(Hb + (size_t)row * C + c0);
        acc8(a, hu, d * d);
    }

    int ei = rowbeg[row];
    const int ee = rowend[row];
    for (; ei + 3 < ee; ei += 4) {
        int2 e0 = edata[ei];
        int2 e1 = edata[ei + 1];
        int2 e2 = edata[ei + 2];
        int2 e3 = edata[ei + 3];
        uint4 u0 = *(const uint4*)(Hb + (size_t)e0.x * C + c0);
        uint4 u1 = *(const uint4*)(Hb + (size_t)e1.x * C + c0);
        uint4 u2 = *(const uint4*)(Hb + (size_t)e2.x * C + c0);
        uint4 u3 = *(const uint4*)(Hb + (size_t)e3.x * C + c0);
        acc8(a, u0, bits2f((unsigned int)e0.y));
        acc8(a, u1, bits2f((unsigned int)e1.y));
        acc8(a, u2, bits2f((unsigned int)e2.y));
        acc8(a, u3, bits2f((unsigned int)e3.y));
    }
    for (; ei < ee; ++ei) {
        int2 e0 = edata[ei];
        uint4 u0 = *(const uint4*)(Hb + (size_t)e0.x * C + c0);
        acc8(a, u0, bits2f((unsigned int)e0.y));
    }

    // + bias
    float4 bv0 = *(const float4*)(bias + c0);
    float4 bv1 = *(const float4*)(bias + c0 + 4);
    a[0] += bv0.x; a[1] += bv0.y; a[2] += bv0.z; a[3] += bv0.w;
    a[4] += bv1.x; a[5] += bv1.y; a[6] += bv1.z; a[7] += bv1.w;

    // LayerNorm across the 16-lane group (128 cols)
    float s = 0.f, sq = 0.f;
    #pragma unroll
    for (int j = 0; j < 8; ++j) { s += a[j]; sq += a[j] * a[j]; }
    #pragma unroll
    for (int off = 8; off >= 1; off >>= 1) {
        s  += __shfl_xor(s, off, 64);
        sq += __shfl_xor(sq, off, 64);
    }
    float mu = s * (1.0f / C);
    float var = sq * (1.0f / C) - mu * mu;
    float rstd = rsqrtf(var + 1e-5f);

    float4 gv0 = *(const float4*)(g + c0);
    float4 gv1 = *(const float4*)(g + c0 + 4);
    float4 be0 = *(const float4*)(beta + c0);
    float4 be1 = *(const float4*)(beta + c0 + 4);
    float gg[8] = {gv0.x, gv0.y, gv0.z, gv0.w, gv1.x, gv1.y, gv1.z, gv1.w};
    float bb[8] = {be0.x, be0.y, be0.z, be0.w, be1.x, be1.y, be1.z, be1.w};

    #pragma unroll
    for (int j = 0; j < 8; ++j) {
        float v = (a[j] - mu) * rstd * gg[j] + bb[j];
        t[j] = 0.5f * v * (1.0f + erff(v * 0.70710678118654752f));
    }
}

// ---------------- gcn_norm + CSR build ----------------

__global__ void k_zero(int* __restrict__ cnt, int* __restrict__ cursor, int n) {
    int i = blockIdx.x * blockDim.x + threadIdx.x;
    if (i < n) cnt[i] = 0;
    if (i == 0) *cursor = 0;
}

__global__ void k_cnt(const int* __restrict__ dst, int* __restrict__ cnt, int e) {
    int i = blockIdx.x * blockDim.x + threadIdx.x;
    if (i < e) atomicAdd(&cnt[dst[i]], 1);
}

__global__ void k_dis_reserve(const int* __restrict__ cnt, float* __restrict__ dis,
                              int* __restrict__ rowbeg, int* __restrict__ rowcur,
                              int* __restrict__ cursor, int n) {
    int i = blockIdx.x * blockDim.x + threadIdx.x;
    if (i < n) {
        dis[i] = rsqrtf((float)cnt[i] + 1.0f);
        int b = atomicAdd(cursor, cnt[i]);
        rowbeg[i] = b;
        rowcur[i] = b;
    }
}

__global__ void k_place(const int* __restrict__ src, const int* __restrict__ dst,
                        const float* __restrict__ ew, const float* __restrict__ dis,
                        int* __restrict__ rowcur, int2* __restrict__ edata, int e) {
    int i = blockIdx.x * blockDim.x + threadIdx.x;
    if (i >= e) return;
    int s = src[i], d = dst[i];
    int p = atomicAdd(&rowcur[d], 1);
    float w = dis[s] * ew[i] * dis[d];
    union { float f; int i; } wb; wb.f = w;
    edata[p] = make_int2(s, wb.i);
}

// ---------------- W pack (both weights in one launch) ----------------
__global__ void k_pack_w2(const float* __restrict__ W1, const float* __restrict__ W2,
                          unsigned short* __restrict__ W1p, unsigned short* __restrict__ W2p) {
    int idx = blockIdx.x * blockDim.x + threadIdx.x;
    const float* W = (idx < C * C) ? W1 : W2;
    unsigned short* Wp = (idx < C * C) ? W1p : W2p;
    int p = idx & (C * C - 1);
    int j = p & 7;
    int l = (p >> 3) & 63;
    int t = p >> 9;           // ct*4 + ks
    int ks = t & 3, ct = t >> 2;
    int k = ks * 32 + ((l >> 4) << 3) + j;
    int c = (ct << 4) + (l & 15);
    Wp[p] = f2b(W[k * C + c]);
}

// ---------------- MFMA GEMM: Hb[n,128](bf16) = bf16(X[n,128]) @ Wp ----------------
__global__ __launch_bounds__(256) void k_gemm_mfma(
    const float* __restrict__ X, const unsigned short* __restrict__ Wp,
    unsigned short* __restrict__ Hb, int n) {
    __shared__ unsigned short xs[32 * C];
    const int tid = threadIdx.x;
    const int base = blockIdx.x * 32;

    const float4* Xv = (const float4*)(X + (size_t)base * C);
    #pragma unroll
    for (int i = 0; i < 4; ++i) {
        int idx4 = i * 256 + tid;
        int elem = idx4 * 4;
        int r = elem >> 7, c = elem & 127;
        float4 v = make_float4(0.f, 0.f, 0.f, 0.f);
        if (base + r < n) v = Xv[idx4];
        ushort4_t pkt;
        pkt.x = f2b(v.x); pkt.y = f2b(v.y); pkt.z = f2b(v.z); pkt.w = f2b(v.w);
        int byte = (r * 256 + c * 2) ^ ((r & 7) << 4);
        *(ushort4_t*)((char*)xs + byte) = pkt;
    }
    __syncthreads();

    const int lane = tid & 63;
    const int wid = tid >> 6;
    const int wm = wid >> 1;
    const int wn = wid & 1;
    const int arow = wm * 16 + (lane & 15);
    const int kg = lane >> 4;

    f32x4 acc[4] = {f32x4{0,0,0,0}, f32x4{0,0,0,0}, f32x4{0,0,0,0}, f32x4{0,0,0,0}};

    #pragma unroll
    for (int ks = 0; ks < 4; ++ks) {
        int abyte = (arow * 256 + ks * 64 + kg * 16) ^ ((arow & 7) << 4);
        short8 a = *(const short8*)((const char*)xs + abyte);
        #pragma unroll
        for (int nt = 0; nt < 4; ++nt) {
            int ct = wn * 4 + nt;
            short8 b = *(const short8*)(Wp + (size_t)((ct * 4 + ks) * 64 + lane) * 8);
            acc[nt] = __builtin_amdgcn_mfma_f32_16x16x32_bf16(a, b, acc[nt], 0, 0, 0);
        }
    }

    const int rbase = base + wm * 16 + kg * 4;
    #pragma unroll
    for (int nt = 0; nt < 4; ++nt) {
        int col = wn * 64 + nt * 16 + (lane & 15);
        #pragma unroll
        for (int r = 0; r < 4; ++r) {
            int row = rbase + r;
            if (row >= n) continue;
            Hb[(size_t)row * C + col] = f2b(acc[nt][r]);
        }
    }
}

// ---------------- fused: agg+bias+LN+GELU (layer-1 params) -> LDS -> GEMM (W2) ----------------
// 512 threads, 32 rows per block: phase A is ONE pass (8 waves x 4 rows), phase B is
// an 8-wave MFMA GEMM (2 waves x 4 waves over 32x128 tile).
__global__ __launch_bounds__(512) void k_fused_agg_gemm(
    const int* __restrict__ rowbeg, const int* __restrict__ rowend,
    const int2* __restrict__ edata,
    const unsigned short* __restrict__ Hb_in, const float* __restrict__ dis,
    const float* __restrict__ bias, const float* __restrict__ g,
    const float* __restrict__ beta,
    const unsigned short* __restrict__ Wp, unsigned short* __restrict__ Hb_out, int n) {
    __shared__ unsigned short xs[32 * C];  // 8 KB, XOR-swizzled
    const int tid = threadIdx.x;
    const int lane = tid & 63;
    const int wid = tid >> 6;           // 0..7
    const int grp = lane >> 4;          // 0..3
    const int sub = lane & 15;
    const int base = blockIdx.x * 32;
    const int c0 = sub * 8;

    // phase A: aggregate + LN + GELU 32 rows in one pass, pack bf16 into swizzled LDS
    {
        int r = wid * 4 + grp;          // 0..31
        int row = base + r;
        float t[8] = {0.f, 0.f, 0.f, 0.f, 0.f, 0.f, 0.f, 0.f};
        if (row < n)
            agg_ln_gelu_row(row, c0, rowbeg, rowend, edata, Hb_in, dis, bias, g, beta, t);
        ushort8_t pkt;
        #pragma unroll
        for (int j = 0; j < 8; ++j) pkt[j] = f2b(t[j]);
        int byte = (r * 256 + c0 * 2) ^ ((r & 7) << 4);
        *(ushort8_t*)((char*)xs + byte) = pkt;
    }
    __syncthreads();

    // phase B: 8-wave MFMA GEMM from LDS. wm = row half (16 rows), wn = col quarter (32 cols).
    const int wm = wid >> 2;            // 0..1
    const int wn = wid & 3;             // 0..3
    const int arow = wm * 16 + (lane & 15);
    const int kg = lane >> 4;

    f32x4 acc[2] = {f32x4{0,0,0,0}, f32x4{0,0,0,0}};

    #pragma unroll
    for (int ks = 0; ks < 4; ++ks) {
        int abyte = (arow * 256 + ks * 64 + kg * 16) ^ ((arow & 7) << 4);
        short8 a = *(const short8*)((const char*)xs + abyte);
        #pragma unroll
        for (int nt = 0; nt < 2; ++nt) {
            int ct = wn * 2 + nt;
            short8 b = *(const short8*)(Wp + (size_t)((ct * 4 + ks) * 64 + lane) * 8);
            acc[nt] = __builtin_amdgcn_mfma_f32_16x16x32_bf16(a, b, acc[nt], 0, 0, 0);
        }
    }

    const int rbase = base + wm * 16 + kg * 4;
    #pragma unroll
    for (int nt = 0; nt < 2; ++nt) {
        int col = wn * 32 + nt * 16 + (lane & 15);
        #pragma unroll
        for (int r = 0; r < 4; ++r) {
            int row = rbase + r;
            if (row >= n) continue;
            Hb_out[(size_t)row * C + col] = f2b(acc[nt][r]);
        }
    }
}

// ---------------- final: aggregate + bias + LN + GELU + residual -> f32 out ----------------
// 16 lanes/row, 4 rows/wave, 16 rows/block. NT on resid/Out (pure streams, no later reader).
__global__ __launch_bounds__(256) void k_agg_ln_gelu(
    const int* __restrict__ rowbeg, const int* __restrict__ rowend,
    const int2* __restrict__ edata,
    const unsigned short* __restrict__ Hb, const float* __restrict__ dis,
    const float* __restrict__ bias, const float* __restrict__ g,
    const float* __restrict__ beta, const float* __restrict__ resid,
    float* __restrict__ Out, int n) {
    const int lane = threadIdx.x & 63;
    const int wid = threadIdx.x >> 6;
    const int grp = lane >> 4;
    const int sub = lane & 15;
    const int row = blockIdx.x * 16 + wid * 4 + grp;
    if (row >= n) return;
    const int c0 = sub * 8;

    float t[8];
    agg_ln_gelu_row(row, c0, rowbeg, rowend, edata, Hb, dis, bias, g, beta, t);

    f32x4 r0 = __builtin_nontemporal_load((const f32x4*)(resid + (size_t)row * C + c0));
    f32x4 r1 = __builtin_nontemporal_load((const f32x4*)(resid + (size_t)row * C + c0 + 4));
    f32x4 o0 = {t[0] + r0.x, t[1] + r0.y, t[2] + r0.z, t[3] + r0.w};
    f32x4 o1 = {t[4] + r1.x, t[5] + r1.y, t[6] + r1.z, t[7] + r1.w};
    __builtin_nontemporal_store(o0, (f32x4*)(Out + (size_t)row * C + c0));
    __builtin_nontemporal_store(o1, (f32x4*)(Out + (size_t)row * C + c0 + 4));
}

// ---------------- launch ----------------

extern "C" void kernel_launch(void* const* d_in, const int* in_sizes, int n_in,
                              void* d_out, int out_size, void* d_ws, size_t ws_size,
                              hipStream_t stream) {
    const float* x      = (const float*)d_in[0];
    const int*   eidx   = (const int*)d_in[1];
    const float* ew     = (const float*)d_in[2];
    const float* W1     = (const float*)d_in[3];
    const float* b1     = (const float*)d_in[4];
    const float* g1     = (const float*)d_in[5];
    const float* beta1  = (const float*)d_in[6];
    const float* W2     = (const float*)d_in[7];
    const float* b2     = (const float*)d_in[8];
    const float* g2     = (const float*)d_in[9];
    const float* beta2  = (const float*)d_in[10];

    const int n = in_sizes[0] / C;
    const int e = in_sizes[2];
    const int* src = eidx;
    const int* dst = eidx + e;

    float* out = (float*)d_out;

    // workspace layout (256B-aligned chunks)
    char* p = (char*)d_ws;
    auto alloc = [&](size_t bytes) {
        char* q = p;
        p += (bytes + 255) & ~(size_t)255;
        return q;
    };
    float* dis    = (float*)alloc(sizeof(float) * n);
    int*   cnt    = (int*)alloc(sizeof(int) * n);
    int*   rowbeg = (int*)alloc(sizeof(int) * n);
    int*   rowcur = (int*)alloc(sizeof(int) * n);   // becomes rowend after k_place
    int2*  edata  = (int2*)alloc(sizeof(int2) * e);
    unsigned short* Hb1 = (unsigned short*)alloc(sizeof(unsigned short) * (size_t)n * C);
    unsigned short* Hb2 = (unsigned short*)alloc(sizeof(unsigned short) * (size_t)n * C);
    unsigned short* W1p = (unsigned short*)alloc(sizeof(unsigned short) * C * C);
    unsigned short* W2p = (unsigned short*)alloc(sizeof(unsigned short) * C * C);
    int*   cursor = (int*)alloc(sizeof(int));

    const int B = 256;
    const int gn = (n + B - 1) / B;
    const int ge = (e + B - 1) / B;

    // gcn_norm + CSR
    k_zero<<<gn, B, 0, stream>>>(cnt, cursor, n);
    k_cnt<<<ge, B, 0, stream>>>(dst, cnt, e);
    k_dis_reserve<<<gn, B, 0, stream>>>(cnt, dis, rowbeg, rowcur, cursor, n);
    k_place<<<ge, B, 0, stream>>>(src, dst, ew, dis, rowcur, edata, e);

    // pack weights (both in one launch)
    k_pack_w2<<<(2 * C * C) / B, B, 0, stream>>>(W1, W2, W1p, W2p);

    // layer-1 GEMM: Hb1 = bf16(x @ W1)
    k_gemm_mfma<<<(n + 31) / 32, B, 0, stream>>>(x, W1p, Hb1, n);

    // fused: h_act1 = GELU(LN(agg(Hb1)+b1)); Hb2 = bf16(h_act1 @ W2)
    k_fused_agg_gemm<<<(n + 31) / 32, 512, 0, stream>>>(rowbeg, rowcur, edata, Hb1, dis,
                                                        b1, g1, beta1, W2p, Hb2, n);

    // final: out = GELU(LN(agg(Hb2)+b2)) + x
    k_agg_ln_gelu<<<(n + 15) / 16, B, 0, stream>>>(rowbeg, rowcur, edata, Hb2, dis,
                                                   b2, g2, beta2, x, out, n);
}

// Round 13
// 185.608 us; speedup vs baseline: 1.6299x; 1.0063x over previous
//
#include <hip/hip_runtime.h>
#include <math.h>

#define C 128

typedef __attribute__((ext_vector_type(8))) short short8;
typedef __attribute__((ext_vector_type(4))) float f32x4;
typedef __attribute__((ext_vector_type(4))) unsigned short ushort4_t;
typedef __attribute__((ext_vector_type(8))) unsigned short ushort8_t;

__device__ inline unsigned short f2b(float f) {
    union { float f; unsigned int u; } v; v.f = f;
    unsigned int u = v.u;
    return (unsigned short)((u + 0x7FFFu + ((u >> 16) & 1u)) >> 16);  // RNE
}
__device__ inline float bits2f(unsigned int u) {
    union { unsigned int u; float f; } v; v.u = u; return v.f;
}

// accumulate 8 bf16 (packed in uint4) scaled by s into a[0..7]
__device__ inline void acc8(float* a, uint4 u, float s) {
    a[0] += s * bits2f(u.x << 16); a[1] += s * bits2f(u.x & 0xFFFF0000u);
    a[2] += s * bits2f(u.y << 16); a[3] += s * bits2f(u.y & 0xFFFF0000u);
    a[4] += s * bits2f(u.z << 16); a[5] += s * bits2f(u.z & 0xFFFF0000u);
    a[6] += s * bits2f(u.w << 16); a[7] += s * bits2f(u.w & 0xFFFF0000u);
}

// ---------------- dual-row worker: aggregate + bias + LN + GELU for rows (rowA, rowA+1) ----
// 16 lanes cooperate; this lane covers cols c0..c0+7 of both rows. Results in tA[8], tB[8].
// Caller guarantees rowA < n. vB = (rowA+1 < n).
__device__ inline void agg_ln_gelu_row2(
    int rowA, int c0, int n,
    const int* __restrict__ rowbeg, const int* __restrict__ rowend,
    const int2* __restrict__ edata, const unsigned short* __restrict__ Hb,
    const float* __restrict__ dis, const float* __restrict__ bias,
    const float* __restrict__ g, const float* __restrict__ beta,
    float* tA, float* tB, bool* vBout) {
    const int rowB = rowA + 1;
    const bool vB = rowB < n;
    *vBout = vB;
    const int rB = vB ? rowB : rowA;

    float aA[8] = {0.f,0.f,0.f,0.f,0.f,0.f,0.f,0.f};
    float aB[8] = {0.f,0.f,0.f,0.f,0.f,0.f,0.f,0.f};

    // self-loops
    {
        float dA = dis[rowA];
        float dBv = dis[rB];
        uint4 hA = *(const uint4*)(Hb + (size_t)rowA * C + c0);
        uint4 hB = *(const uint4*)(Hb + (size_t)rB * C + c0);
        acc8(aA, hA, dA * dA);
        acc8(aB, hB, vB ? dBv * dBv : 0.f);
    }

    int ca = rowbeg[rowA];
    const int ea = rowend[rowA];
    int cb = vB ? rowbeg[rB] : 0;
    const int eb = vB ? rowend[rB] : 0;

    while (ca < ea || cb < eb) {
        bool vA0 = ca < ea,     vA1 = ca + 1 < ea;
        bool vB0 = cb < eb,     vB1 = cb + 1 < eb;
        int iA0 = vA0 ? ca     : 0;
        int iA1 = vA1 ? ca + 1 : 0;
        int iB0 = vB0 ? cb     : 0;
        int iB1 = vB1 ? cb + 1 : 0;
        int2 eA0 = edata[iA0];
        int2 eA1 = edata[iA1];
        int2 eB0 = edata[iB0];
        int2 eB1 = edata[iB1];
        uint4 uA0 = *(const uint4*)(Hb + (size_t)eA0.x * C + c0);
        uint4 uA1 = *(const uint4*)(Hb + (size_t)eA1.x * C + c0);
        uint4 uB0 = *(const uint4*)(Hb + (size_t)eB0.x * C + c0);
        uint4 uB1 = *(const uint4*)(Hb + (size_t)eB1.x * C + c0);
        float wA0 = vA0 ? bits2f((unsigned int)eA0.y) : 0.f;
        float wA1 = vA1 ? bits2f((unsigned int)eA1.y) : 0.f;
        float wB0 = vB0 ? bits2f((unsigned int)eB0.y) : 0.f;
        float wB1 = vB1 ? bits2f((unsigned int)eB1.y) : 0.f;
        acc8(aA, uA0, wA0);
        acc8(aA, uA1, wA1);
        acc8(aB, uB0, wB0);
        acc8(aB, uB1, wB1);
        ca += 2;
        cb += 2;
    }

    // + bias (shared columns)
    float4 bv0 = *(const float4*)(bias + c0);
    float4 bv1 = *(const float4*)(bias + c0 + 4);
    float bbias[8] = {bv0.x, bv0.y, bv0.z, bv0.w, bv1.x, bv1.y, bv1.z, bv1.w};
    #pragma unroll
    for (int j = 0; j < 8; ++j) { aA[j] += bbias[j]; aB[j] += bbias[j]; }

    // two LayerNorm reductions across the 16-lane group
    float sA = 0.f, qA = 0.f, sB = 0.f, qB = 0.f;
    #pragma unroll
    for (int j = 0; j < 8; ++j) {
        sA += aA[j]; qA += aA[j] * aA[j];
        sB += aB[j]; qB += aB[j] * aB[j];
    }
    #pragma unroll
    for (int off = 8; off >= 1; off >>= 1) {
        sA += __shfl_xor(sA, off, 64);
        qA += __shfl_xor(qA, off, 64);
        sB += __shfl_xor(sB, off, 64);
        qB += __shfl_xor(qB, off, 64);
    }
    float muA = sA * (1.0f / C);
    float rstdA = rsqrtf(qA * (1.0f / C) - muA * muA + 1e-5f);
    float muB = sB * (1.0f / C);
    float rstdB = rsqrtf(qB * (1.0f / C) - muB * muB + 1e-5f);

    float4 gv0 = *(const float4*)(g + c0);
    float4 gv1 = *(const float4*)(g + c0 + 4);
    float4 be0 = *(const float4*)(beta + c0);
    float4 be1 = *(const float4*)(beta + c0 + 4);
    float gg[8] = {gv0.x, gv0.y, gv0.z, gv0.w, gv1.x, gv1.y, gv1.z, gv1.w};
    float bb[8] = {be0.x, be0.y, be0.z, be0.w, be1.x, be1.y, be1.z, be1.w};

    #pragma unroll
    for (int j = 0; j < 8; ++j) {
        float vA = (aA[j] - muA) * rstdA * gg[j] + bb[j];
        float vBv = (aB[j] - muB) * rstdB * gg[j] + bb[j];
        tA[j] = 0.5f * vA * (1.0f + erff(vA * 0.70710678118654752f));
        tB[j] = 0.5f * vBv * (1.0f + erff(vBv * 0.70710678118654752f));
    }
}

// ---------------- gcn_norm + CSR build ----------------

__global__ void k_zero(int* __restrict__ cnt, int* __restrict__ cursor, int n) {
    int i = blockIdx.x * blockDim.x + threadIdx.x;
    if (i < n) cnt[i] = 0;
    if (i == 0) *cursor = 0;
}

__global__ void k_cnt(const int* __restrict__ dst, int* __restrict__ cnt, int e) {
    int i = blockIdx.x * blockDim.x + threadIdx.x;
    if (i < e) atomicAdd(&cnt[dst[i]], 1);
}

__global__ void k_dis_reserve(const int* __restrict__ cnt, float* __restrict__ dis,
                              int* __restrict__ rowbeg, int* __restrict__ rowcur,
                              int* __restrict__ cursor, int n) {
    int i = blockIdx.x * blockDim.x + threadIdx.x;
    if (i < n) {
        dis[i] = rsqrtf((float)cnt[i] + 1.0f);
        int b = atomicAdd(cursor, cnt[i]);
        rowbeg[i] = b;
        rowcur[i] = b;
    }
}

__global__ void k_place(const int* __restrict__ src, const int* __restrict__ dst,
                        const float* __restrict__ ew, const float* __restrict__ dis,
                        int* __restrict__ rowcur, int2* __restrict__ edata, int e) {
    int i = blockIdx.x * blockDim.x + threadIdx.x;
    if (i >= e) return;
    int s = src[i], d = dst[i];
    int p = atomicAdd(&rowcur[d], 1);
    float w = dis[s] * ew[i] * dis[d];
    union { float f; int i; } wb; wb.f = w;
    edata[p] = make_int2(s, wb.i);
}

// ---------------- W pack (both weights in one launch) ----------------
__global__ void k_pack_w2(const float* __restrict__ W1, const float* __restrict__ W2,
                          unsigned short* __restrict__ W1p, unsigned short* __restrict__ W2p) {
    int idx = blockIdx.x * blockDim.x + threadIdx.x;
    const float* W = (idx < C * C) ? W1 : W2;
    unsigned short* Wp = (idx < C * C) ? W1p : W2p;
    int p = idx & (C * C - 1);
    int j = p & 7;
    int l = (p >> 3) & 63;
    int t = p >> 9;           // ct*4 + ks
    int ks = t & 3, ct = t >> 2;
    int k = ks * 32 + ((l >> 4) << 3) + j;
    int c = (ct << 4) + (l & 15);
    Wp[p] = f2b(W[k * C + c]);
}

// ---------------- MFMA GEMM: Hb[n,128](bf16) = bf16(X[n,128]) @ Wp ----------------
__global__ __launch_bounds__(256) void k_gemm_mfma(
    const float* __restrict__ X, const unsigned short* __restrict__ Wp,
    unsigned short* __restrict__ Hb, int n) {
    __shared__ unsigned short xs[32 * C];
    const int tid = threadIdx.x;
    const int base = blockIdx.x * 32;

    const float4* Xv = (const float4*)(X + (size_t)base * C);
    #pragma unroll
    for (int i = 0; i < 4; ++i) {
        int idx4 = i * 256 + tid;
        int elem = idx4 * 4;
        int r = elem >> 7, c = elem & 127;
        float4 v = make_float4(0.f, 0.f, 0.f, 0.f);
        if (base + r < n) v = Xv[idx4];
        ushort4_t pkt;
        pkt.x = f2b(v.x); pkt.y = f2b(v.y); pkt.z = f2b(v.z); pkt.w = f2b(v.w);
        int byte = (r * 256 + c * 2) ^ ((r & 7) << 4);
        *(ushort4_t*)((char*)xs + byte) = pkt;
    }
    __syncthreads();

    const int lane = tid & 63;
    const int wid = tid >> 6;
    const int wm = wid >> 1;
    const int wn = wid & 1;
    const int arow = wm * 16 + (lane & 15);
    const int kg = lane >> 4;

    f32x4 acc[4] = {f32x4{0,0,0,0}, f32x4{0,0,0,0}, f32x4{0,0,0,0}, f32x4{0,0,0,0}};

    #pragma unroll
    for (int ks = 0; ks < 4; ++ks) {
        int abyte = (arow * 256 + ks * 64 + kg * 16) ^ ((arow & 7) << 4);
        short8 a = *(const short8*)((const char*)xs + abyte);
        #pragma unroll
        for (int nt = 0; nt < 4; ++nt) {
            int ct = wn * 4 + nt;
            short8 b = *(const short8*)(Wp + (size_t)((ct * 4 + ks) * 64 + lane) * 8);
            acc[nt] = __builtin_amdgcn_mfma_f32_16x16x32_bf16(a, b, acc[nt], 0, 0, 0);
        }
    }

    const int rbase = base + wm * 16 + kg * 4;
    #pragma unroll
    for (int nt = 0; nt < 4; ++nt) {
        int col = wn * 64 + nt * 16 + (lane & 15);
        #pragma unroll
        for (int r = 0; r < 4; ++r) {
            int row = rbase + r;
            if (row >= n) continue;
            Hb[(size_t)row * C + col] = f2b(acc[nt][r]);
        }
    }
}

// ---------------- fused: agg+bias+LN+GELU (layer-1 params) -> LDS -> GEMM (W2) ----------------
// 512 threads, 64 rows per block: phase A = 8 waves x 4 groups x 2 interleaved rows,
// phase B = 8-wave MFMA GEMM over the 64x128 tile.
__global__ __launch_bounds__(512) void k_fused_agg_gemm(
    const int* __restrict__ rowbeg, const int* __restrict__ rowend,
    const int2* __restrict__ edata,
    const unsigned short* __restrict__ Hb_in, const float* __restrict__ dis,
    const float* __restrict__ bias, const float* __restrict__ g,
    const float* __restrict__ beta,
    const unsigned short* __restrict__ Wp, unsigned short* __restrict__ Hb_out, int n) {
    __shared__ unsigned short xs[64 * C];  // 16 KB, XOR-swizzled
    const int tid = threadIdx.x;
    const int lane = tid & 63;
    const int wid = tid >> 6;           // 0..7
    const int grp = lane >> 4;          // 0..3
    const int sub = lane & 15;
    const int base = blockIdx.x * 64;
    const int c0 = sub * 8;

    // phase A
    {
        int pair = wid * 4 + grp;       // 0..31
        int rA = pair * 2;              // 0..62 (block-local)
        int rowA = base + rA;
        float tA[8] = {0,0,0,0,0,0,0,0};
        float tB[8] = {0,0,0,0,0,0,0,0};
        bool vB = false;
        if (rowA < n)
            agg_ln_gelu_row2(rowA, c0, n, rowbeg, rowend, edata, Hb_in, dis,
                             bias, g, beta, tA, tB, &vB);
        ushort8_t pA, pB;
        #pragma unroll
        for (int j = 0; j < 8; ++j) { pA[j] = f2b(tA[j]); pB[j] = f2b(tB[j]); }
        int rBl = rA + 1;
        int byteA = (rA * 256 + c0 * 2) ^ ((rA & 7) << 4);
        int byteB = (rBl * 256 + c0 * 2) ^ ((rBl & 7) << 4);
        *(ushort8_t*)((char*)xs + byteA) = pA;
        *(ushort8_t*)((char*)xs + byteB) = pB;
    }
    __syncthreads();

    // phase B: 8 waves: wm = wid>>1 (row tile of 16), wn = wid&1 (col half of 64)
    const int wm = wid >> 1;            // 0..3
    const int wn = wid & 1;             // 0..1
    const int arow = wm * 16 + (lane & 15);
    const int kg = lane >> 4;

    f32x4 acc[4] = {f32x4{0,0,0,0}, f32x4{0,0,0,0}, f32x4{0,0,0,0}, f32x4{0,0,0,0}};

    #pragma unroll
    for (int ks = 0; ks < 4; ++ks) {
        int abyte = (arow * 256 + ks * 64 + kg * 16) ^ ((arow & 7) << 4);
        short8 a = *(const short8*)((const char*)xs + abyte);
        #pragma unroll
        for (int nt = 0; nt < 4; ++nt) {
            int ct = wn * 4 + nt;
            short8 b = *(const short8*)(Wp + (size_t)((ct * 4 + ks) * 64 + lane) * 8);
            acc[nt] = __builtin_amdgcn_mfma_f32_16x16x32_bf16(a, b, acc[nt], 0, 0, 0);
        }
    }

    const int rbase = base + wm * 16 + kg * 4;
    #pragma unroll
    for (int nt = 0; nt < 4; ++nt) {
        int col = wn * 64 + nt * 16 + (lane & 15);
        #pragma unroll
        for (int r = 0; r < 4; ++r) {
            int row = rbase + r;
            if (row >= n) continue;
            Hb_out[(size_t)row * C + col] = f2b(acc[nt][r]);
        }
    }
}

// ---------------- final: aggregate + bias + LN + GELU + residual -> f32 out ----------------
// 256 threads, 32 rows/block: 4 waves x 4 groups x 2 interleaved rows.
__global__ __launch_bounds__(256) void k_agg_ln_gelu(
    const int* __restrict__ rowbeg, const int* __restrict__ rowend,
    const int2* __restrict__ edata,
    const unsigned short* __restrict__ Hb, const float* __restrict__ dis,
    const float* __restrict__ bias, const float* __restrict__ g,
    const float* __restrict__ beta, const float* __restrict__ resid,
    float* __restrict__ Out, int n) {
    const int lane = threadIdx.x & 63;
    const int wid = threadIdx.x >> 6;
    const int grp = lane >> 4;
    const int sub = lane & 15;
    const int pair = blockIdx.x * 16 + wid * 4 + grp;
    const int rowA = pair * 2;
    if (rowA >= n) return;
    const int c0 = sub * 8;

    float tA[8], tB[8];
    bool vB = false;
    agg_ln_gelu_row2(rowA, c0, n, rowbeg, rowend, edata, Hb, dis,
                     bias, g, beta, tA, tB, &vB);

    {
        float4 r0 = *(const float4*)(resid + (size_t)rowA * C + c0);
        float4 r1 = *(const float4*)(resid + (size_t)rowA * C + c0 + 4);
        *(float4*)(Out + (size_t)rowA * C + c0) =
            make_float4(tA[0] + r0.x, tA[1] + r0.y, tA[2] + r0.z, tA[3] + r0.w);
        *(float4*)(Out + (size_t)rowA * C + c0 + 4) =
            make_float4(tA[4] + r1.x, tA[5] + r1.y, tA[6] + r1.z, tA[7] + r1.w);
    }
    if (vB) {
        int rowB = rowA + 1;
        float4 r0 = *(const float4*)(resid + (size_t)rowB * C + c0);
        float4 r1 = *(const float4*)(resid + (size_t)rowB * C + c0 + 4);
        *(float4*)(Out + (size_t)rowB * C + c0) =
            make_float4(tB[0] + r0.x, tB[1] + r0.y, tB[2] + r0.z, tB[3] + r0.w);
        *(float4*)(Out + (size_t)rowB * C + c0 + 4) =
            make_float4(tB[4] + r1.x, tB[5] + r1.y, tB[6] + r1.z, tB[7] + r1.w);
    }
}

// ---------------- launch ----------------

extern "C" void kernel_launch(void* const* d_in, const int* in_sizes, int n_in,
                              void* d_out, int out_size, void* d_ws, size_t ws_size,
                              hipStream_t stream) {
    const float* x      = (const float*)d_in[0];
    const int*   eidx   = (const int*)d_in[1];
    const float* ew     = (const float*)d_in[2];
    const float* W1     = (const float*)d_in[3];
    const float* b1     = (const float*)d_in[4];
    const float* g1     = (const float*)d_in[5];
    const float* beta1  = (const float*)d_in[6];
    const float* W2     = (const float*)d_in[7];
    const float* b2     = (const float*)d_in[8];
    const float* g2     = (const float*)d_in[9];
    const float* beta2  = (const float*)d_in[10];

    const int n = in_sizes[0] / C;
    const int e = in_sizes[2];
    const int* src = eidx;
    const int* dst = eidx + e;

    float* out = (float*)d_out;

    // workspace layout (256B-aligned chunks)
    char* p = (char*)d_ws;
    auto alloc = [&](size_t bytes) {
        char* q = p;
        p += (bytes + 255) & ~(size_t)255;
        return q;
    };
    float* dis    = (float*)alloc(sizeof(float) * n);
    int*   cnt    = (int*)alloc(sizeof(int) * n);
    int*   rowbeg = (int*)alloc(sizeof(int) * n);
    int*   rowcur = (int*)alloc(sizeof(int) * n);   // becomes rowend after k_place
    int2*  edata  = (int2*)alloc(sizeof(int2) * e);
    unsigned short* Hb1 = (unsigned short*)alloc(sizeof(unsigned short) * (size_t)n * C);
    unsigned short* Hb2 = (unsigned short*)alloc(sizeof(unsigned short) * (size_t)n * C);
    unsigned short* W1p = (unsigned short*)alloc(sizeof(unsigned short) * C * C);
    unsigned short* W2p = (unsigned short*)alloc(sizeof(unsigned short) * C * C);
    int*   cursor = (int*)alloc(sizeof(int));

    const int B = 256;
    const int gn = (n + B - 1) / B;
    const int ge = (e + B - 1) / B;

    // gcn_norm + CSR
    k_zero<<<gn, B, 0, stream>>>(cnt, cursor, n);
    k_cnt<<<ge, B, 0, stream>>>(dst, cnt, e);
    k_dis_reserve<<<gn, B, 0, stream>>>(cnt, dis, rowbeg, rowcur, cursor, n);
    k_place<<<ge, B, 0, stream>>>(src, dst, ew, dis, rowcur, edata, e);

    // pack weights (both in one launch)
    k_pack_w2<<<(2 * C * C) / B, B, 0, stream>>>(W1, W2, W1p, W2p);

    // layer-1 GEMM: Hb1 = bf16(x @ W1)
    k_gemm_mfma<<<(n + 31) / 32, B, 0, stream>>>(x, W1p, Hb1, n);

    // fused: h_act1 = GELU(LN(agg(Hb1)+b1)); Hb2 = bf16(h_act1 @ W2)
    k_fused_agg_gemm<<<(n + 63) / 64, 512, 0, stream>>>(rowbeg, rowcur, edata, Hb1, dis,
                                                        b1, g1, beta1, W2p, Hb2, n);

    // final: out = GELU(LN(agg(Hb2)+b2)) + x
    k_agg_ln_gelu<<<(n + 31) / 32, B, 0, stream>>>(rowbeg, rowcur, edata, Hb2, dis,
                                                   b2, g2, beta2, x, out, n);
}

// Round 14
// 160.342 us; speedup vs baseline: 1.8867x; 1.1576x over previous
//
#include <hip/hip_runtime.h>
#include <math.h>

#define C 128
#define CAPF 1024   // fused kernel LDS edge cap (32 rows, mean ~166 edges)
#define CAPA 512    // final kernel LDS edge cap (16 rows, mean ~83 edges)

typedef __attribute__((ext_vector_type(8))) short short8;
typedef __attribute__((ext_vector_type(4))) float f32x4;
typedef __attribute__((ext_vector_type(4))) unsigned short ushort4_t;
typedef __attribute__((ext_vector_type(8))) unsigned short ushort8_t;

__device__ inline unsigned short f2b(float f) {
    union { float f; unsigned int u; } v; v.f = f;
    unsigned int u = v.u;
    return (unsigned short)((u + 0x7FFFu + ((u >> 16) & 1u)) >> 16);  // RNE
}
__device__ inline float bits2f(unsigned int u) {
    union { unsigned int u; float f; } v; v.u = u; return v.f;
}

// accumulate 8 bf16 (packed in uint4) scaled by s into a[0..7]
__device__ inline void acc8(float* a, uint4 u, float s) {
    a[0] += s * bits2f(u.x << 16); a[1] += s * bits2f(u.x & 0xFFFF0000u);
    a[2] += s * bits2f(u.y << 16); a[3] += s * bits2f(u.y & 0xFFFF0000u);
    a[4] += s * bits2f(u.z << 16); a[5] += s * bits2f(u.z & 0xFFFF0000u);
    a[6] += s * bits2f(u.w << 16); a[7] += s * bits2f(u.w & 0xFFFF0000u);
}

// ---------------- row worker: aggregate + bias + LN + GELU, edata staged in LDS ------------
// 16 lanes cooperate on one row; lane covers cols c0..c0+7. Block-local edge range
// [kbeg,kend); entries < cap come from LDS eds, the (essentially never) overflow from global.
__device__ inline void agg_row_lds(
    int row, int c0, int kbeg, int kend, int eb0, int cap,
    const int2* __restrict__ eds, const int2* __restrict__ edata,
    const unsigned short* __restrict__ Hb, const float* __restrict__ dis,
    const float* __restrict__ bias, const float* __restrict__ g,
    const float* __restrict__ beta, float* t) {
    float a[8] = {0.f, 0.f, 0.f, 0.f, 0.f, 0.f, 0.f, 0.f};

    // self-loop: dis^2 * Hb[row]
    {
        float d = dis[row];
        uint4 hu = *(const uint4*)(Hb + (size_t)row * C + c0);
        acc8(a, hu, d * d);
    }

    const int kc = kend < cap ? kend : cap;
    int k = kbeg;
    for (; k + 3 < kc; k += 4) {
        int2 e0 = eds[k];
        int2 e1 = eds[k + 1];
        int2 e2 = eds[k + 2];
        int2 e3 = eds[k + 3];
        uint4 u0 = *(const uint4*)(Hb + (size_t)e0.x * C + c0);
        uint4 u1 = *(const uint4*)(Hb + (size_t)e1.x * C + c0);
        uint4 u2 = *(const uint4*)(Hb + (size_t)e2.x * C + c0);
        uint4 u3 = *(const uint4*)(Hb + (size_t)e3.x * C + c0);
        acc8(a, u0, bits2f((unsigned int)e0.y));
        acc8(a, u1, bits2f((unsigned int)e1.y));
        acc8(a, u2, bits2f((unsigned int)e2.y));
        acc8(a, u3, bits2f((unsigned int)e3.y));
    }
    for (; k < kc; ++k) {
        int2 e0 = eds[k];
        uint4 u0 = *(const uint4*)(Hb + (size_t)e0.x * C + c0);
        acc8(a, u0, bits2f((unsigned int)e0.y));
    }
    for (; k < kend; ++k) {  // overflow fallback (practically never taken)
        int2 e0 = edata[eb0 + k];
        uint4 u0 = *(const uint4*)(Hb + (size_t)e0.x * C + c0);
        acc8(a, u0, bits2f((unsigned int)e0.y));
    }

    // + bias
    float4 bv0 = *(const float4*)(bias + c0);
    float4 bv1 = *(const float4*)(bias + c0 + 4);
    a[0] += bv0.x; a[1] += bv0.y; a[2] += bv0.z; a[3] += bv0.w;
    a[4] += bv1.x; a[5] += bv1.y; a[6] += bv1.z; a[7] += bv1.w;

    // LayerNorm across the 16-lane group (128 cols)
    float s = 0.f, sq = 0.f;
    #pragma unroll
    for (int j = 0; j < 8; ++j) { s += a[j]; sq += a[j] * a[j]; }
    #pragma unroll
    for (int off = 8; off >= 1; off >>= 1) {
        s  += __shfl_xor(s, off, 64);
        sq += __shfl_xor(sq, off, 64);
    }
    float mu = s * (1.0f / C);
    float var = sq * (1.0f / C) - mu * mu;
    float rstd = rsqrtf(var + 1e-5f);

    float4 gv0 = *(const float4*)(g + c0);
    float4 gv1 = *(const float4*)(g + c0 + 4);
    float4 be0 = *(const float4*)(beta + c0);
    float4 be1 = *(const float4*)(beta + c0 + 4);
    float gg[8] = {gv0.x, gv0.y, gv0.z, gv0.w, gv1.x, gv1.y, gv1.z, gv1.w};
    float bb[8] = {be0.x, be0.y, be0.z, be0.w, be1.x, be1.y, be1.z, be1.w};

    #pragma unroll
    for (int j = 0; j < 8; ++j) {
        float v = (a[j] - mu) * rstd * gg[j] + bb[j];
        t[j] = 0.5f * v * (1.0f + erff(v * 0.70710678118654752f));
    }
}

// ================= CSR build: count -> scan -> place (row-ordered segments) =================

__global__ void k_zero(int* __restrict__ cnt, int n) {
    int i = blockIdx.x * blockDim.x + threadIdx.x;
    if (i < n) cnt[i] = 0;
}

__global__ void k_cnt(const int* __restrict__ dst, int* __restrict__ cnt, int e) {
    int i = blockIdx.x * blockDim.x + threadIdx.x;
    if (i < e) atomicAdd(&cnt[dst[i]], 1);
}

// per-256-block scan: rowbeg gets block-local exclusive, blocksum gets block total
__global__ __launch_bounds__(256) void k_scan_a(const int* __restrict__ cnt,
                                                int* __restrict__ rowbeg,
                                                int* __restrict__ blocksum, int n) {
    const int tid = threadIdx.x;
    const int i = blockIdx.x * 256 + tid;
    const int lane = tid & 63, wv = tid >> 6;
    int v = (i < n) ? cnt[i] : 0;
    int x = v;
    #pragma unroll
    for (int off = 1; off < 64; off <<= 1) {
        int y = __shfl_up(x, off, 64);
        if (lane >= off) x += y;
    }
    __shared__ int wsum[4];
    if (lane == 63) wsum[wv] = x;
    __syncthreads();
    int woff = 0;
    #pragma unroll
    for (int k = 0; k < 4; ++k) if (k < wv) woff += wsum[k];
    int incl = x + woff;
    if (i < n) rowbeg[i] = incl - v;
    if (tid == 255) blocksum[blockIdx.x] = incl;
}

// single-block scan of blocksums (nb <= 512) -> exclusive offsets in place
__global__ __launch_bounds__(512) void k_scan_b(int* __restrict__ bs, int nb) {
    const int tid = threadIdx.x;
    __shared__ int s[512];
    int v = (tid < nb) ? bs[tid] : 0;
    s[tid] = v;
    __syncthreads();
    for (int off = 1; off < 512; off <<= 1) {
        int t = 0;
        if (tid >= off) t = s[tid - off];
        __syncthreads();
        s[tid] += t;
        __syncthreads();
    }
    if (tid < nb) bs[tid] = s[tid] - v;  // exclusive
}

// add block offsets; init rowcur; compute dis; write rowbeg[n]
__global__ void k_scan_c(const int* __restrict__ cnt, const int* __restrict__ bs,
                         int* __restrict__ rowbeg, int* __restrict__ rowcur,
                         float* __restrict__ dis, int n) {
    int i = blockIdx.x * blockDim.x + threadIdx.x;
    if (i >= n) return;
    int rb = rowbeg[i] + bs[i >> 8];
    rowbeg[i] = rb;
    rowcur[i] = rb;
    dis[i] = rsqrtf((float)cnt[i] + 1.0f);
    if (i == n - 1) rowbeg[n] = rb + cnt[i];
}

__global__ void k_place(const int* __restrict__ src, const int* __restrict__ dst,
                        const float* __restrict__ ew, const float* __restrict__ dis,
                        int* __restrict__ rowcur, int2* __restrict__ edata, int e) {
    int i = blockIdx.x * blockDim.x + threadIdx.x;
    if (i >= e) return;
    int s = src[i], d = dst[i];
    int p = atomicAdd(&rowcur[d], 1);
    float w = dis[s] * ew[i] * dis[d];
    union { float f; int i; } wb; wb.f = w;
    edata[p] = make_int2(s, wb.i);
}

// ================= W pack (both weights in one launch) =================
__global__ void k_pack_w2(const float* __restrict__ W1, const float* __restrict__ W2,
                          unsigned short* __restrict__ W1p, unsigned short* __restrict__ W2p) {
    int idx = blockIdx.x * blockDim.x + threadIdx.x;
    const float* W = (idx < C * C) ? W1 : W2;
    unsigned short* Wp = (idx < C * C) ? W1p : W2p;
    int p = idx & (C * C - 1);
    int j = p & 7;
    int l = (p >> 3) & 63;
    int t = p >> 9;           // ct*4 + ks
    int ks = t & 3, ct = t >> 2;
    int k = ks * 32 + ((l >> 4) << 3) + j;
    int c = (ct << 4) + (l & 15);
    Wp[p] = f2b(W[k * C + c]);
}

// ================= MFMA GEMM: Hb[n,128](bf16) = bf16(X[n,128]) @ Wp =================
__global__ __launch_bounds__(256) void k_gemm_mfma(
    const float* __restrict__ X, const unsigned short* __restrict__ Wp,
    unsigned short* __restrict__ Hb, int n) {
    __shared__ unsigned short xs[32 * C];
    const int tid = threadIdx.x;
    const int base = blockIdx.x * 32;

    const float4* Xv = (const float4*)(X + (size_t)base * C);
    #pragma unroll
    for (int i = 0; i < 4; ++i) {
        int idx4 = i * 256 + tid;
        int elem = idx4 * 4;
        int r = elem >> 7, c = elem & 127;
        float4 v = make_float4(0.f, 0.f, 0.f, 0.f);
        if (base + r < n) v = Xv[idx4];
        ushort4_t pkt;
        pkt.x = f2b(v.x); pkt.y = f2b(v.y); pkt.z = f2b(v.z); pkt.w = f2b(v.w);
        int byte = (r * 256 + c * 2) ^ ((r & 7) << 4);
        *(ushort4_t*)((char*)xs + byte) = pkt;
    }
    __syncthreads();

    const int lane = tid & 63;
    const int wid = tid >> 6;
    const int wm = wid >> 1;
    const int wn = wid & 1;
    const int arow = wm * 16 + (lane & 15);
    const int kg = lane >> 4;

    f32x4 acc[4] = {f32x4{0,0,0,0}, f32x4{0,0,0,0}, f32x4{0,0,0,0}, f32x4{0,0,0,0}};

    #pragma unroll
    for (int ks = 0; ks < 4; ++ks) {
        int abyte = (arow * 256 + ks * 64 + kg * 16) ^ ((arow & 7) << 4);
        short8 a = *(const short8*)((const char*)xs + abyte);
        #pragma unroll
        for (int nt = 0; nt < 4; ++nt) {
            int ct = wn * 4 + nt;
            short8 b = *(const short8*)(Wp + (size_t)((ct * 4 + ks) * 64 + lane) * 8);
            acc[nt] = __builtin_amdgcn_mfma_f32_16x16x32_bf16(a, b, acc[nt], 0, 0, 0);
        }
    }

    const int rbase = base + wm * 16 + kg * 4;
    #pragma unroll
    for (int nt = 0; nt < 4; ++nt) {
        int col = wn * 64 + nt * 16 + (lane & 15);
        #pragma unroll
        for (int r = 0; r < 4; ++r) {
            int row = rbase + r;
            if (row >= n) continue;
            Hb[(size_t)row * C + col] = f2b(acc[nt][r]);
        }
    }
}

// ========== fused: LDS-staged agg+bias+LN+GELU (layer-1) -> LDS -> GEMM (W2) ==========
// 512 threads, 32 rows/block: stage block's contiguous edge range into LDS, then
// phase A = 8 waves x 4 groups x 1 row, phase B = 8-wave MFMA GEMM over 32x128 tile.
__global__ __launch_bounds__(512) void k_fused_agg_gemm(
    const int* __restrict__ rowbeg, const int2* __restrict__ edata,
    const unsigned short* __restrict__ Hb_in, const float* __restrict__ dis,
    const float* __restrict__ bias, const float* __restrict__ g,
    const float* __restrict__ beta,
    const unsigned short* __restrict__ Wp, unsigned short* __restrict__ Hb_out, int n) {
    __shared__ unsigned short xs[32 * C];  // 8 KB
    __shared__ int2 eds[CAPF];             // 8 KB
    const int tid = threadIdx.x;
    const int lane = tid & 63;
    const int wid = tid >> 6;           // 0..7
    const int grp = lane >> 4;          // 0..3
    const int sub = lane & 15;
    const int base = blockIdx.x * 32;
    const int c0 = sub * 8;

    // stage edata (contiguous range for rows [base, base+32))
    const int eb0 = rowbeg[base];
    const int top = (base + 32 < n) ? base + 32 : n;
    const int len = rowbeg[top] - eb0;
    const int lcap = len < CAPF ? len : CAPF;
    for (int i = tid; i < lcap; i += 512) eds[i] = edata[eb0 + i];
    __syncthreads();

    // phase A
    {
        int r = wid * 4 + grp;          // 0..31
        int row = base + r;
        float t[8] = {0.f, 0.f, 0.f, 0.f, 0.f, 0.f, 0.f, 0.f};
        if (row < n) {
            int kbeg = rowbeg[row] - eb0;
            int kend = rowbeg[row + 1] - eb0;
            agg_row_lds(row, c0, kbeg, kend, eb0, CAPF, eds, edata,
                        Hb_in, dis, bias, g, beta, t);
        }
        ushort8_t pkt;
        #pragma unroll
        for (int j = 0; j < 8; ++j) pkt[j] = f2b(t[j]);
        int byte = (r * 256 + c0 * 2) ^ ((r & 7) << 4);
        *(ushort8_t*)((char*)xs + byte) = pkt;
    }
    __syncthreads();

    // phase B: 8-wave MFMA GEMM. wm = row half (16 rows), wn = col quarter (32 cols).
    const int wm = wid >> 2;            // 0..1
    const int wn = wid & 3;             // 0..3
    const int arow = wm * 16 + (lane & 15);
    const int kg = lane >> 4;

    f32x4 acc[2] = {f32x4{0,0,0,0}, f32x4{0,0,0,0}};

    #pragma unroll
    for (int ks = 0; ks < 4; ++ks) {
        int abyte = (arow * 256 + ks * 64 + kg * 16) ^ ((arow & 7) << 4);
        short8 a = *(const short8*)((const char*)xs + abyte);
        #pragma unroll
        for (int nt = 0; nt < 2; ++nt) {
            int ct = wn * 2 + nt;
            short8 b = *(const short8*)(Wp + (size_t)((ct * 4 + ks) * 64 + lane) * 8);
            acc[nt] = __builtin_amdgcn_mfma_f32_16x16x32_bf16(a, b, acc[nt], 0, 0, 0);
        }
    }

    const int rbase = base + wm * 16 + kg * 4;
    #pragma unroll
    for (int nt = 0; nt < 2; ++nt) {
        int col = wn * 32 + nt * 16 + (lane & 15);
        #pragma unroll
        for (int r = 0; r < 4; ++r) {
            int row = rbase + r;
            if (row >= n) continue;
            Hb_out[(size_t)row * C + col] = f2b(acc[nt][r]);
        }
    }
}

// ========== final: LDS-staged agg + bias + LN + GELU + residual -> f32 out ==========
// 256 threads, 16 rows/block: 4 waves x 4 groups x 1 row.
__global__ __launch_bounds__(256) void k_agg_ln_gelu(
    const int* __restrict__ rowbeg, const int2* __restrict__ edata,
    const unsigned short* __restrict__ Hb, const float* __restrict__ dis,
    const float* __restrict__ bias, const float* __restrict__ g,
    const float* __restrict__ beta, const float* __restrict__ resid,
    float* __restrict__ Out, int n) {
    __shared__ int2 eds[CAPA];             // 4 KB
    const int tid = threadIdx.x;
    const int lane = tid & 63;
    const int wid = tid >> 6;
    const int grp = lane >> 4;
    const int sub = lane & 15;
    const int base = blockIdx.x * 16;
    const int c0 = sub * 8;

    const int eb0 = rowbeg[base];
    const int top = (base + 16 < n) ? base + 16 : n;
    const int len = rowbeg[top] - eb0;
    const int lcap = len < CAPA ? len : CAPA;
    for (int i = tid; i < lcap; i += 256) eds[i] = edata[eb0 + i];
    __syncthreads();

    const int row = base + wid * 4 + grp;
    if (row >= n) return;

    int kbeg = rowbeg[row] - eb0;
    int kend = rowbeg[row + 1] - eb0;
    float t[8];
    agg_row_lds(row, c0, kbeg, kend, eb0, CAPA, eds, edata,
                Hb, dis, bias, g, beta, t);

    float4 r0 = *(const float4*)(resid + (size_t)row * C + c0);
    float4 r1 = *(const float4*)(resid + (size_t)row * C + c0 + 4);
    *(float4*)(Out + (size_t)row * C + c0) =
        make_float4(t[0] + r0.x, t[1] + r0.y, t[2] + r0.z, t[3] + r0.w);
    *(float4*)(Out + (size_t)row * C + c0 + 4) =
        make_float4(t[4] + r1.x, t[5] + r1.y, t[6] + r1.z, t[7] + r1.w);
}

// ================= launch =================

extern "C" void kernel_launch(void* const* d_in, const int* in_sizes, int n_in,
                              void* d_out, int out_size, void* d_ws, size_t ws_size,
                              hipStream_t stream) {
    const float* x      = (const float*)d_in[0];
    const int*   eidx   = (const int*)d_in[1];
    const float* ew     = (const float*)d_in[2];
    const float* W1     = (const float*)d_in[3];
    const float* b1     = (const float*)d_in[4];
    const float* g1     = (const float*)d_in[5];
    const float* beta1  = (const float*)d_in[6];
    const float* W2     = (const float*)d_in[7];
    const float* b2     = (const float*)d_in[8];
    const float* g2     = (const float*)d_in[9];
    const float* beta2  = (const float*)d_in[10];

    const int n = in_sizes[0] / C;
    const int e = in_sizes[2];
    const int* src = eidx;
    const int* dst = eidx + e;

    float* out = (float*)d_out;

    // workspace layout (256B-aligned chunks)
    char* p = (char*)d_ws;
    auto alloc = [&](size_t bytes) {
        char* q = p;
        p += (bytes + 255) & ~(size_t)255;
        return q;
    };
    float* dis      = (float*)alloc(sizeof(float) * n);
    int*   cnt      = (int*)alloc(sizeof(int) * n);
    int*   rowbeg   = (int*)alloc(sizeof(int) * (n + 1));
    int*   rowcur   = (int*)alloc(sizeof(int) * n);
    int*   blocksum = (int*)alloc(sizeof(int) * 512);
    int2*  edata    = (int2*)alloc(sizeof(int2) * e);
    unsigned short* Hb1 = (unsigned short*)alloc(sizeof(unsigned short) * (size_t)n * C);
    unsigned short* Hb2 = (unsigned short*)alloc(sizeof(unsigned short) * (size_t)n * C);
    unsigned short* W1p = (unsigned short*)alloc(sizeof(unsigned short) * C * C);
    unsigned short* W2p = (unsigned short*)alloc(sizeof(unsigned short) * C * C);

    const int B = 256;
    const int gn = (n + B - 1) / B;   // scan block count (391 <= 512)
    const int ge = (e + B - 1) / B;

    // CSR build (row-ordered segments via prefix sum)
    k_zero<<<gn, B, 0, stream>>>(cnt, n);
    k_cnt<<<ge, B, 0, stream>>>(dst, cnt, e);
    k_scan_a<<<gn, B, 0, stream>>>(cnt, rowbeg, blocksum, n);
    k_scan_b<<<1, 512, 0, stream>>>(blocksum, gn);
    k_scan_c<<<gn, B, 0, stream>>>(cnt, blocksum, rowbeg, rowcur, dis, n);
    k_place<<<ge, B, 0, stream>>>(src, dst, ew, dis, rowcur, edata, e);

    // pack weights
    k_pack_w2<<<(2 * C * C) / B, B, 0, stream>>>(W1, W2, W1p, W2p);

    // layer-1 GEMM: Hb1 = bf16(x @ W1)
    k_gemm_mfma<<<(n + 31) / 32, B, 0, stream>>>(x, W1p, Hb1, n);

    // fused: h_act1 = GELU(LN(agg(Hb1)+b1)); Hb2 = bf16(h_act1 @ W2)
    k_fused_agg_gemm<<<(n + 31) / 32, 512, 0, stream>>>(rowbeg, edata, Hb1, dis,
                                                        b1, g1, beta1, W2p, Hb2, n);

    // final: out = GELU(LN(agg(Hb2)+b2)) + x
    k_agg_ln_gelu<<<(n + 15) / 16, B, 0, stream>>>(rowbeg, edata, Hb2, dis,
                                                   b2, g2, beta2, x, out, n);
}

// Round 15
// 154.986 us; speedup vs baseline: 1.9519x; 1.0346x over previous
//
#include <hip/hip_runtime.h>
#include <math.h>

#define C 128
#define CAPF 1024   // LDS edge cap per 32-row block (mean ~166 edges)
#define DSTRIDE 132 // padded f32 LDS row stride for GEMM output

typedef __attribute__((ext_vector_type(8))) short short8;
typedef __attribute__((ext_vector_type(4))) float f32x4;
typedef __attribute__((ext_vector_type(4))) unsigned short ushort4_t;
typedef __attribute__((ext_vector_type(8))) unsigned short ushort8_t;

__device__ inline unsigned short f2b(float f) {
    union { float f; unsigned int u; } v; v.f = f;
    unsigned int u = v.u;
    return (unsigned short)((u + 0x7FFFu + ((u >> 16) & 1u)) >> 16);  // RNE
}
__device__ inline float bits2f(unsigned int u) {
    union { unsigned int u; float f; } v; v.u = u; return v.f;
}

// accumulate 8 bf16 (packed in uint4) scaled by s into a[0..7]
__device__ inline void acc8(float* a, uint4 u, float s) {
    a[0] += s * bits2f(u.x << 16); a[1] += s * bits2f(u.x & 0xFFFF0000u);
    a[2] += s * bits2f(u.y << 16); a[3] += s * bits2f(u.y & 0xFFFF0000u);
    a[4] += s * bits2f(u.z << 16); a[5] += s * bits2f(u.z & 0xFFFF0000u);
    a[6] += s * bits2f(u.w << 16); a[7] += s * bits2f(u.w & 0xFFFF0000u);
}

// ---------------- agg-only row worker (no bias/LN): 16 lanes/row, lane covers c0..c0+7 ----
__device__ inline void agg_row_only(
    int row, int c0, int kbeg, int kend, int eb0,
    const int2* __restrict__ eds, const int2* __restrict__ edata,
    const unsigned short* __restrict__ Hb, const float* __restrict__ dis, float* a) {
    // self-loop: dis^2 * Hb[row]
    {
        float d = dis[row];
        uint4 hu = *(const uint4*)(Hb + (size_t)row * C + c0);
        acc8(a, hu, d * d);
    }
    const int kc = kend < CAPF ? kend : CAPF;
    int k = kbeg;
    for (; k + 3 < kc; k += 4) {
        int2 e0 = eds[k];
        int2 e1 = eds[k + 1];
        int2 e2 = eds[k + 2];
        int2 e3 = eds[k + 3];
        uint4 u0 = *(const uint4*)(Hb + (size_t)e0.x * C + c0);
        uint4 u1 = *(const uint4*)(Hb + (size_t)e1.x * C + c0);
        uint4 u2 = *(const uint4*)(Hb + (size_t)e2.x * C + c0);
        uint4 u3 = *(const uint4*)(Hb + (size_t)e3.x * C + c0);
        acc8(a, u0, bits2f((unsigned int)e0.y));
        acc8(a, u1, bits2f((unsigned int)e1.y));
        acc8(a, u2, bits2f((unsigned int)e2.y));
        acc8(a, u3, bits2f((unsigned int)e3.y));
    }
    for (; k < kc; ++k) {
        int2 e0 = eds[k];
        uint4 u0 = *(const uint4*)(Hb + (size_t)e0.x * C + c0);
        acc8(a, u0, bits2f((unsigned int)e0.y));
    }
    for (; k < kend; ++k) {  // overflow fallback (practically never taken)
        int2 e0 = edata[eb0 + k];
        uint4 u0 = *(const uint4*)(Hb + (size_t)e0.x * C + c0);
        acc8(a, u0, bits2f((unsigned int)e0.y));
    }
}

// ================= CSR build: count(+x convert) -> scan -> place =================

__global__ void k_zero(int* __restrict__ cnt, int n) {
    int i = blockIdx.x * blockDim.x + threadIdx.x;
    if (i < n) cnt[i] = 0;
}

// blocks [0,bc): convert x -> bf16 xb (8 elems/thread); blocks [bc,..): degree count
__global__ void k_cnt_cvt(const int* __restrict__ dst, int* __restrict__ cnt, int e, int bc,
                          const float* __restrict__ x, unsigned short* __restrict__ xb,
                          int ncvt8) {
    const int bid = blockIdx.x;
    const int tid = threadIdx.x;
    if (bid < bc) {
        int i = bid * 256 + tid;
        if (i < ncvt8) {
            const float4* xp = (const float4*)(x + (size_t)i * 8);
            float4 v0 = xp[0];
            float4 v1 = xp[1];
            ushort8_t pkt;
            pkt[0] = f2b(v0.x); pkt[1] = f2b(v0.y); pkt[2] = f2b(v0.z); pkt[3] = f2b(v0.w);
            pkt[4] = f2b(v1.x); pkt[5] = f2b(v1.y); pkt[6] = f2b(v1.z); pkt[7] = f2b(v1.w);
            *(ushort8_t*)(xb + (size_t)i * 8) = pkt;
        }
    } else {
        int i = (bid - bc) * 256 + tid;
        if (i < e) atomicAdd(&cnt[dst[i]], 1);
    }
}

// per-256-block scan: rowbeg gets block-local exclusive, blocksum gets block total
__global__ __launch_bounds__(256) void k_scan_a(const int* __restrict__ cnt,
                                                int* __restrict__ rowbeg,
                                                int* __restrict__ blocksum, int n) {
    const int tid = threadIdx.x;
    const int i = blockIdx.x * 256 + tid;
    const int lane = tid & 63, wv = tid >> 6;
    int v = (i < n) ? cnt[i] : 0;
    int x = v;
    #pragma unroll
    for (int off = 1; off < 64; off <<= 1) {
        int y = __shfl_up(x, off, 64);
        if (lane >= off) x += y;
    }
    __shared__ int wsum[4];
    if (lane == 63) wsum[wv] = x;
    __syncthreads();
    int woff = 0;
    #pragma unroll
    for (int k = 0; k < 4; ++k) if (k < wv) woff += wsum[k];
    int incl = x + woff;
    if (i < n) rowbeg[i] = incl - v;
    if (tid == 255) blocksum[blockIdx.x] = incl;
}

// block 0: scan of blocksums (nb <= 512) in place; blocks 1..: pack W1/W2 to frag layout
__global__ __launch_bounds__(512) void k_scan_b_pack(int* __restrict__ bs, int nb,
    const float* __restrict__ W1, const float* __restrict__ W2,
    unsigned short* __restrict__ W1p, unsigned short* __restrict__ W2p) {
    const int tid = threadIdx.x;
    if (blockIdx.x == 0) {
        __shared__ int s[512];
        int v = (tid < nb) ? bs[tid] : 0;
        s[tid] = v;
        __syncthreads();
        for (int off = 1; off < 512; off <<= 1) {
            int t = 0;
            if (tid >= off) t = s[tid - off];
            __syncthreads();
            s[tid] += t;
            __syncthreads();
        }
        if (tid < nb) bs[tid] = s[tid] - v;  // exclusive
    } else {
        int idx = (blockIdx.x - 1) * 512 + tid;      // 0 .. 2*C*C-1
        const float* W = (idx < C * C) ? W1 : W2;
        unsigned short* Wp = (idx < C * C) ? W1p : W2p;
        int p = idx & (C * C - 1);
        int j = p & 7;
        int l = (p >> 3) & 63;
        int t = p >> 9;           // ct*4 + ks
        int ks = t & 3, ct = t >> 2;
        int k = ks * 32 + ((l >> 4) << 3) + j;
        int c = (ct << 4) + (l & 15);
        Wp[p] = f2b(W[k * C + c]);
    }
}

// add block offsets; init rowcur; compute dis; write rowbeg[n]
__global__ void k_scan_c(const int* __restrict__ cnt, const int* __restrict__ bs,
                         int* __restrict__ rowbeg, int* __restrict__ rowcur,
                         float* __restrict__ dis, int n) {
    int i = blockIdx.x * blockDim.x + threadIdx.x;
    if (i >= n) return;
    int rb = rowbeg[i] + bs[i >> 8];
    rowbeg[i] = rb;
    rowcur[i] = rb;
    dis[i] = rsqrtf((float)cnt[i] + 1.0f);
    if (i == n - 1) rowbeg[n] = rb + cnt[i];
}

__global__ void k_place(const int* __restrict__ src, const int* __restrict__ dst,
                        const float* __restrict__ ew, const float* __restrict__ dis,
                        int* __restrict__ rowcur, int2* __restrict__ edata, int e) {
    int i = blockIdx.x * blockDim.x + threadIdx.x;
    if (i >= e) return;
    int s = src[i], d = dst[i];
    int p = atomicAdd(&rowcur[d], 1);
    float w = dis[s] * ew[i] * dis[d];
    union { float f; int i; } wb; wb.f = w;
    edata[p] = make_int2(s, wb.i);
}

// ========== layer kernel: agg(Xin) -> @W -> +bias -> LN -> GELU [-> +resid] ==========
// 512 threads, 32 rows/block. Uses agg∘W commutativity: agg(X@W) == agg(X)@W.
// If out_f32 != nullptr: adds bf16 residual xb_resid and writes f32 out.
// Else: writes bf16 out_bf16.
__global__ __launch_bounds__(512) void k_layer(
    const int* __restrict__ rowbeg, const int2* __restrict__ edata,
    const unsigned short* __restrict__ Xin, const float* __restrict__ dis,
    const unsigned short* __restrict__ Wp,
    const float* __restrict__ bias, const float* __restrict__ g,
    const float* __restrict__ beta,
    const unsigned short* __restrict__ xb_resid,
    unsigned short* __restrict__ out_bf16, float* __restrict__ out_f32, int n) {
    __shared__ int2 eds[CAPF];                 // 8 KB
    __shared__ unsigned short xs[32 * C];      // 8 KB, XOR-swizzled (GEMM A input)
    __shared__ float dacc[32 * DSTRIDE];       // 16.9 KB (GEMM output rows)
    const int tid = threadIdx.x;
    const int lane = tid & 63;
    const int wid = tid >> 6;           // 0..7
    const int grp = lane >> 4;          // 0..3
    const int sub = lane & 15;
    const int base = blockIdx.x * 32;
    const int c0 = sub * 8;

    // stage this block's contiguous edge range into LDS
    const int eb0 = rowbeg[base];
    const int top = (base + 32 < n) ? base + 32 : n;
    const int len = rowbeg[top] - eb0;
    const int lcap = len < CAPF ? len : CAPF;
    for (int i = tid; i < lcap; i += 512) eds[i] = edata[eb0 + i];
    __syncthreads();

    // phase A: aggregate 32 rows (1 row per 16-lane group), pack bf16 into swizzled LDS
    {
        int r = wid * 4 + grp;          // 0..31
        int row = base + r;
        float a[8] = {0.f, 0.f, 0.f, 0.f, 0.f, 0.f, 0.f, 0.f};
        if (row < n) {
            int kbeg = rowbeg[row] - eb0;
            int kend = rowbeg[row + 1] - eb0;
            agg_row_only(row, c0, kbeg, kend, eb0, eds, edata, Xin, dis, a);
        }
        ushort8_t pkt;
        #pragma unroll
        for (int j = 0; j < 8; ++j) pkt[j] = f2b(a[j]);
        int byte = (r * 256 + c0 * 2) ^ ((r & 7) << 4);
        *(ushort8_t*)((char*)xs + byte) = pkt;
    }
    __syncthreads();

    // phase B: 8-wave MFMA GEMM (32x128) = xs @ Wp; write f32 + bias into dacc
    {
        const int wm = wid >> 2;        // 0..1 (row tile of 16)
        const int wn = wid & 3;         // 0..3 (col quarter of 32)
        const int arow = wm * 16 + (lane & 15);
        const int kg = lane >> 4;

        f32x4 acc[2] = {f32x4{0,0,0,0}, f32x4{0,0,0,0}};

        #pragma unroll
        for (int ks = 0; ks < 4; ++ks) {
            int abyte = (arow * 256 + ks * 64 + kg * 16) ^ ((arow & 7) << 4);
            short8 av = *(const short8*)((const char*)xs + abyte);
            #pragma unroll
            for (int nt = 0; nt < 2; ++nt) {
                int ct = wn * 2 + nt;
                short8 bv = *(const short8*)(Wp + (size_t)((ct * 4 + ks) * 64 + lane) * 8);
                acc[nt] = __builtin_amdgcn_mfma_f32_16x16x32_bf16(av, bv, acc[nt], 0, 0, 0);
            }
        }

        const int rb = wm * 16 + kg * 4;   // block-local output row base
        #pragma unroll
        for (int nt = 0; nt < 2; ++nt) {
            int col = wn * 32 + nt * 16 + (lane & 15);
            float bv = bias[col];
            #pragma unroll
            for (int r2 = 0; r2 < 4; ++r2)
                dacc[(rb + r2) * DSTRIDE + col] = acc[nt][r2] + bv;
        }
    }
    __syncthreads();

    // phase C: LN + GELU per row from dacc (16 lanes/row), then epilogue
    {
        int r = wid * 4 + grp;
        int row = base + r;
        if (row >= n) return;

        const float* dp = dacc + r * DSTRIDE + c0;
        float4 v0 = *(const float4*)(dp);
        float4 v1 = *(const float4*)(dp + 4);
        float a[8] = {v0.x, v0.y, v0.z, v0.w, v1.x, v1.y, v1.z, v1.w};

        float s = 0.f, sq = 0.f;
        #pragma unroll
        for (int j = 0; j < 8; ++j) { s += a[j]; sq += a[j] * a[j]; }
        #pragma unroll
        for (int off = 8; off >= 1; off >>= 1) {
            s  += __shfl_xor(s, off, 64);
            sq += __shfl_xor(sq, off, 64);
        }
        float mu = s * (1.0f / C);
        float var = sq * (1.0f / C) - mu * mu;
        float rstd = rsqrtf(var + 1e-5f);

        float4 gv0 = *(const float4*)(g + c0);
        float4 gv1 = *(const float4*)(g + c0 + 4);
        float4 be0 = *(const float4*)(beta + c0);
        float4 be1 = *(const float4*)(beta + c0 + 4);
        float gg[8] = {gv0.x, gv0.y, gv0.z, gv0.w, gv1.x, gv1.y, gv1.z, gv1.w};
        float bb[8] = {be0.x, be0.y, be0.z, be0.w, be1.x, be1.y, be1.z, be1.w};

        float t[8];
        #pragma unroll
        for (int j = 0; j < 8; ++j) {
            float v = (a[j] - mu) * rstd * gg[j] + bb[j];
            t[j] = 0.5f * v * (1.0f + erff(v * 0.70710678118654752f));
        }

        if (out_f32 != nullptr) {
            ushort8_t rv = *(const ushort8_t*)(xb_resid + (size_t)row * C + c0);
            #pragma unroll
            for (int j = 0; j < 8; ++j)
                t[j] += bits2f(((unsigned int)(unsigned short)rv[j]) << 16);
            *(float4*)(out_f32 + (size_t)row * C + c0) = make_float4(t[0], t[1], t[2], t[3]);
            *(float4*)(out_f32 + (size_t)row * C + c0 + 4) = make_float4(t[4], t[5], t[6], t[7]);
        } else {
            ushort8_t pkt;
            #pragma unroll
            for (int j = 0; j < 8; ++j) pkt[j] = f2b(t[j]);
            *(ushort8_t*)(out_bf16 + (size_t)row * C + c0) = pkt;
        }
    }
}

// ================= launch =================

extern "C" void kernel_launch(void* const* d_in, const int* in_sizes, int n_in,
                              void* d_out, int out_size, void* d_ws, size_t ws_size,
                              hipStream_t stream) {
    const float* x      = (const float*)d_in[0];
    const int*   eidx   = (const int*)d_in[1];
    const float* ew     = (const float*)d_in[2];
    const float* W1     = (const float*)d_in[3];
    const float* b1     = (const float*)d_in[4];
    const float* g1     = (const float*)d_in[5];
    const float* beta1  = (const float*)d_in[6];
    const float* W2     = (const float*)d_in[7];
    const float* b2     = (const float*)d_in[8];
    const float* g2     = (const float*)d_in[9];
    const float* beta2  = (const float*)d_in[10];

    const int n = in_sizes[0] / C;
    const int e = in_sizes[2];
    const int* src = eidx;
    const int* dst = eidx + e;

    float* out = (float*)d_out;

    // workspace layout (256B-aligned chunks)
    char* p = (char*)d_ws;
    auto alloc = [&](size_t bytes) {
        char* q = p;
        p += (bytes + 255) & ~(size_t)255;
        return q;
    };
    float* dis      = (float*)alloc(sizeof(float) * n);
    int*   cnt      = (int*)alloc(sizeof(int) * n);
    int*   rowbeg   = (int*)alloc(sizeof(int) * (n + 1));
    int*   rowcur   = (int*)alloc(sizeof(int) * n);
    int*   blocksum = (int*)alloc(sizeof(int) * 512);
    int2*  edata    = (int2*)alloc(sizeof(int2) * e);
    unsigned short* xb    = (unsigned short*)alloc(sizeof(unsigned short) * (size_t)n * C);
    unsigned short* hact1 = (unsigned short*)alloc(sizeof(unsigned short) * (size_t)n * C);
    unsigned short* W1p   = (unsigned short*)alloc(sizeof(unsigned short) * C * C);
    unsigned short* W2p   = (unsigned short*)alloc(sizeof(unsigned short) * C * C);

    const int B = 256;
    const int gn = (n + B - 1) / B;     // scan block count (391 <= 512)
    const int ge = (e + B - 1) / B;
    const int ncvt8 = n * C / 8;        // 8-elem convert items
    const int bc = (ncvt8 + B - 1) / B; // convert blocks

    // CSR build (row-ordered segments) + x->bf16 convert folded into the count launch
    k_zero<<<gn, B, 0, stream>>>(cnt, n);
    k_cnt_cvt<<<bc + ge, B, 0, stream>>>(dst, cnt, e, bc, x, xb, ncvt8);
    k_scan_a<<<gn, B, 0, stream>>>(cnt, rowbeg, blocksum, n);
    k_scan_b_pack<<<1 + (2 * C * C) / 512, 512, 0, stream>>>(blocksum, gn, W1, W2, W1p, W2p);
    k_scan_c<<<gn, B, 0, stream>>>(cnt, blocksum, rowbeg, rowcur, dis, n);
    k_place<<<ge, B, 0, stream>>>(src, dst, ew, dis, rowcur, edata, e);

    // layer 1: hact1 = GELU(LN(agg(xb) @ W1 + b1))
    k_layer<<<(n + 31) / 32, 512, 0, stream>>>(rowbeg, edata, xb, dis, W1p,
                                               b1, g1, beta1, nullptr,
                                               hact1, nullptr, n);

    // layer 2: out = GELU(LN(agg(hact1) @ W2 + b2)) + x
    k_layer<<<(n + 31) / 32, 512, 0, stream>>>(rowbeg, edata, hact1, dis, W2p,
                                               b2, g2, beta2, xb,
                                               nullptr, out, n);
}